// Round 9
// baseline (145.083 us; speedup 1.0000x reference)
//
#include <hip/hip_runtime.h>
#include <hip/hip_bf16.h>

typedef __bf16 bf16_t;
typedef __bf16 bf16x8 __attribute__((ext_vector_type(8)));
typedef __bf16 bf16x4 __attribute__((ext_vector_type(4)));
typedef float f32x4 __attribute__((ext_vector_type(4)));
typedef int vint4 __attribute__((ext_vector_type(4)));

#define AS1 __attribute__((address_space(1)))
#define AS3 __attribute__((address_space(3)))

constexpr int B_ = 2, T_ = 4096, E_ = 1024, H_ = 16;
constexpr int M_ = B_ * T_;   // 8192 token rows

// Compact per-scale partial buffers (elem offsets). Scale s: B*H*(T>>s) rows.
__device__ constexpr size_t OB_OFF[5]  = {0, 8388608, 12582912, 14680064, 15728640};
__device__ constexpr size_t LSE_OFF[5] = {0, 131072, 196608, 229376, 245760};
constexpr size_t OB_TOTAL  = 16252928;  // elems (bf16)
constexpr size_t LSE_TOTAL = 253952;    // elems (f32)

// ---------------- f32 -> bf16 elementwise ----------------
__global__ __launch_bounds__(256) void cvt_f32_bf16(const float* __restrict__ in,
                                                    bf16_t* __restrict__ out) {
  int i = (blockIdx.x * 256 + threadIdx.x) * 4;
  const float4 v = *(const float4*)(in + i);
  bf16x4 o;
  o[0] = (bf16_t)v.x; o[1] = (bf16_t)v.y; o[2] = (bf16_t)v.z; o[3] = (bf16_t)v.w;
  *(bf16x4*)(out + i) = o;
}

// ---------------- weights: f32 [K][N] -> bf16 [N][K] (transposed) ----------------
__global__ __launch_bounds__(256) void cvt_transpose_w(
    const float* __restrict__ w0, const float* __restrict__ w1,
    const float* __restrict__ w2, const float* __restrict__ w3,
    bf16_t* __restrict__ o0, bf16_t* __restrict__ o1,
    bf16_t* __restrict__ o2, bf16_t* __restrict__ o3) {
  __shared__ float tile[32][33];
  const float* src; bf16_t* dst;
  switch (blockIdx.z) {
    case 0: src = w0; dst = o0; break;
    case 1: src = w1; dst = o1; break;
    case 2: src = w2; dst = o2; break;
    default: src = w3; dst = o3; break;
  }
  const int n0 = blockIdx.x * 32, k0 = blockIdx.y * 32;
  const int tx = threadIdx.x & 31, ty = threadIdx.x >> 5;  // 32 x 8
#pragma unroll
  for (int i = 0; i < 32; i += 8)
    tile[ty + i][tx] = src[(size_t)(k0 + ty + i) * E_ + n0 + tx];
  __syncthreads();
#pragma unroll
  for (int i = 0; i < 32; i += 8)
    dst[(size_t)(n0 + ty + i) * E_ + k0 + tx] = (bf16_t)tile[tx][ty + i];
}

// ---------------- 256x256 8-phase bf16 MFMA GEMM (m201-style schedule) ---------------
// Tile 256x256, BK=64, 512 thr = 8 waves (2M x 4N), wave 128x64, acc[8][4].
// Per K-tile: 4 quadrant-phases. Phase p: {ds_read A-quad p (4 b128; ph0 also reads
// all B: +8 b128, held in regs across the tile) || staged global_load_lds -> barrier
// -> lgkmcnt(0) -> setprio(1) 16 MFMA setprio(0) -> barrier}. One counted vmcnt(6)
// per K-tile at ph3 (never 0 mid-loop).  2 LDS dbufs (tile t in buf t&1).
// Staging placement (race-free by phase-closure):
//   ph0: A-load1(t+1)   [buf (t+1)&1, rows 64-127: tile t-1 fully read]
//   ph1: A-load3(t+1)   [rows 192-255: same argument]
//   ph2: B0,B1,A-load0 (t+2) [B(t) consumed in ph0; rows 0-63 = quads 0,1 closed]
//   ph3: B2,B3,A-load2 (t+2) [rows 128-191 = wm1 quads 0,1 closed]
// vmcnt(6) end-of-tile: 6 loads issued after newest load of t+1 => t+1 landed.
// Source-side XOR swizzle (R6/R8-verified conflict-free): LDS linear, global chunk
// (tid&7)^(row&7), ds_read slot XOR (lc&7).
template <bool OUT_BF16, bool QKV>
__global__ __launch_bounds__(512, 1) void gemm8ph(
    const bf16_t* __restrict__ A, const bf16_t* __restrict__ BT,
    const float* __restrict__ bias0, const float* __restrict__ bias1,
    const float* __restrict__ bias2, void* __restrict__ Cout) {
  constexpr int K = E_;
  constexpr int NT = K / 64;           // 16 K-tiles
  __shared__ bf16_t Sm[65536];         // 2 bufs x (A 16384 | B 16384) elems

  const int tid = threadIdx.x;
  const int lane = tid & 63;
  const int wid = tid >> 6;
  const int wm = wid >> 2, wn = wid & 3;   // 2M x 4N waves, wave tile 128x64
  const int lc = lane & 15, lg = lane >> 4;
  const int bm = blockIdx.x;
  int bn = blockIdx.y;

  const float* bias = bias0;
  float scale = 1.0f;
  void* outp = Cout;
  const bf16_t* Bt = BT;
  if (QKV) {
    const int which = bn >> 2;
    bn &= 3;
    bias = (which == 0) ? bias0 : (which == 1) ? bias1 : bias2;
    scale = (which == 0) ? 0.125f : 1.0f;
    outp = (void*)((bf16_t*)Cout + (size_t)which * M_ * E_);
    Bt += (size_t)which * E_ * E_;
  }

  const int srow = tid >> 3;                      // 0..63
  const int schunk = (tid & 7) ^ (srow & 7);      // source-side swizzle
  const bf16_t* Ag = A + (size_t)(bm * 256 + srow) * K + schunk * 8;
  const bf16_t* Bg = Bt + (size_t)(bn * 256 + srow) * K + schunk * 8;

  // one global_load_lds = 512 thr x 16 B = 8 KB = 64 rows; A/B tile = 4 loads each
  auto ldA = [&](int kt, int l) {
    __builtin_amdgcn_global_load_lds(
        (const AS1 void*)(Ag + (size_t)(l * 64) * K + kt * 64),
        (AS3 void*)(Sm + (kt & 1) * 32768 + l * 4096 + tid * 8), 16, 0, 0);
  };
  auto ldB = [&](int kt, int l) {
    __builtin_amdgcn_global_load_lds(
        (const AS1 void*)(Bg + (size_t)(l * 64) * K + kt * 64),
        (AS3 void*)(Sm + (kt & 1) * 32768 + 16384 + l * 4096 + tid * 8), 16, 0, 0);
  };

  f32x4 acc[8][4] = {};

  // prologue: tile0 full (8), tile1 minus A1/A3 (6); wait tile0 => vmcnt(6)
  ldA(0, 0); ldA(0, 1); ldA(0, 2); ldA(0, 3);
  ldB(0, 0); ldB(0, 1); ldB(0, 2); ldB(0, 3);
  ldB(1, 0); ldB(1, 1); ldB(1, 2); ldB(1, 3);
  ldA(1, 0); ldA(1, 2);
  asm volatile("s_waitcnt vmcnt(6)" ::: "memory");
  __builtin_amdgcn_s_barrier();

  const int sxor = (lc & 7);
  for (int kt = 0; kt < NT; ++kt) {
    const int sa = (kt & 1) * 32768;
    const int sb = sa + 16384;
    const bool st1 = (kt + 1) < NT;
    const bool st2 = (kt + 2) < NT;
    bf16x8 bfr[4][2];

#pragma unroll
    for (int p = 0; p < 4; ++p) {
      asm volatile("" ::: "memory");
      // ---- ds reads for this phase ----
      bf16x8 afr[2][2];
#pragma unroll
      for (int i2 = 0; i2 < 2; ++i2) {
        const int row = wm * 128 + p * 32 + i2 * 16 + lc;
        afr[i2][0] = *(const bf16x8*)&Sm[sa + row * 64 + ((0 * 4 + lg) ^ sxor) * 8];
        afr[i2][1] = *(const bf16x8*)&Sm[sa + row * 64 + ((1 * 4 + lg) ^ sxor) * 8];
      }
      if (p == 0) {
#pragma unroll
        for (int j = 0; j < 4; ++j) {
          const int row = wn * 64 + j * 16 + lc;
          bfr[j][0] = *(const bf16x8*)&Sm[sb + row * 64 + ((0 * 4 + lg) ^ sxor) * 8];
          bfr[j][1] = *(const bf16x8*)&Sm[sb + row * 64 + ((1 * 4 + lg) ^ sxor) * 8];
        }
      }
      // ---- staged prefetch ----
      if (p == 0) { if (st1) ldA(kt + 1, 1); }
      else if (p == 1) { if (st1) ldA(kt + 1, 3); }
      else if (p == 2) { if (st2) { ldB(kt + 2, 0); ldB(kt + 2, 1); ldA(kt + 2, 0); } }
      else             { if (st2) { ldB(kt + 2, 2); ldB(kt + 2, 3); ldA(kt + 2, 2); } }

      __builtin_amdgcn_s_barrier();
      asm volatile("s_waitcnt lgkmcnt(0)" ::: "memory");
      __builtin_amdgcn_s_setprio(1);
#pragma unroll
      for (int i2 = 0; i2 < 2; ++i2)
#pragma unroll
        for (int j = 0; j < 4; ++j) {
          acc[p * 2 + i2][j] = __builtin_amdgcn_mfma_f32_16x16x32_bf16(
              afr[i2][0], bfr[j][0], acc[p * 2 + i2][j], 0, 0, 0);
          acc[p * 2 + i2][j] = __builtin_amdgcn_mfma_f32_16x16x32_bf16(
              afr[i2][1], bfr[j][1], acc[p * 2 + i2][j], 0, 0, 0);
        }
      __builtin_amdgcn_s_setprio(0);
      if (p == 3) {
        if (st2)      asm volatile("s_waitcnt vmcnt(6)" ::: "memory");
        else if (st1) asm volatile("s_waitcnt vmcnt(0)" ::: "memory");
      }
      asm volatile("" ::: "memory");
      __builtin_amdgcn_s_barrier();
    }
  }

#pragma unroll
  for (int i = 0; i < 8; ++i) {
    const int row = bm * 256 + wm * 128 + i * 16 + lg * 4;
#pragma unroll
    for (int j = 0; j < 4; ++j) {
      const int col = bn * 256 + wn * 64 + j * 16 + lc;
      const float bv = bias[col];
#pragma unroll
      for (int rg = 0; rg < 4; ++rg) {
        const float v = (acc[i][j][rg] + bv) * scale;
        if (OUT_BF16)
          ((bf16_t*)outp)[(size_t)(row + rg) * E_ + col] = (bf16_t)v;
        else
          ((float*)outp)[(size_t)(row + rg) * E_ + col] = v;
      }
    }
  }
}

// ---------------- 256x128 pipelined GEMM (out-proj; exact 256-block grid) ------------
template <bool OUT_BF16, bool QKV>
__global__ __launch_bounds__(512, 1) void gemm_dp(
    const bf16_t* __restrict__ A, const bf16_t* __restrict__ BT,
    const float* __restrict__ bias0, const float* __restrict__ bias1,
    const float* __restrict__ bias2, void* __restrict__ Cout) {
  constexpr int K = E_;
  constexpr int NT = K / 64;           // 16 K-tiles
  __shared__ bf16_t Sm[73728];         // A: 3x16384 | B: 3x8192  (147456 B)

  const int tid = threadIdx.x;
  const int lane = tid & 63;
  const int wid = tid >> 6;
  const int wm = wid >> 1, wn = wid & 1;   // 4M x 2N waves
  const int lc = lane & 15, lg = lane >> 4;
  const int bm = blockIdx.x;
  int bn = blockIdx.y;

  const float* bias = bias0;
  float scale = 1.0f;
  void* outp = Cout;
  const bf16_t* Bt = BT;
  if (QKV) {
    const int which = bn >> 3;
    bn &= 7;
    bias = (which == 0) ? bias0 : (which == 1) ? bias1 : bias2;
    scale = (which == 0) ? 0.125f : 1.0f;
    outp = (void*)((bf16_t*)Cout + (size_t)which * M_ * E_);
    Bt += (size_t)which * E_ * E_;
  }

  const int srow = tid >> 3;                      // 0..63
  const int schunk = (tid & 7) ^ (srow & 7);      // source-side swizzle
  const bf16_t* Ag = A + (size_t)(bm * 256 + srow) * K + schunk * 8;
  const bf16_t* Bg = Bt + (size_t)(bn * 128 + srow) * K + schunk * 8;

  auto stA = [&](int kt, int bu) {
#pragma unroll
    for (int l = 0; l < 4; ++l)
      __builtin_amdgcn_global_load_lds(
          (const AS1 void*)(Ag + (size_t)(l * 64) * K + kt * 64),
          (AS3 void*)(Sm + bu * 16384 + l * 4096 + tid * 8), 16, 0, 0);
  };
  auto stB = [&](int kt, int bu) {
#pragma unroll
    for (int l = 0; l < 2; ++l)
      __builtin_amdgcn_global_load_lds(
          (const AS1 void*)(Bg + (size_t)(l * 64) * K + kt * 64),
          (AS3 void*)(Sm + 49152 + bu * 8192 + l * 4096 + tid * 8), 16, 0, 0);
  };

  const int sl0 = ((lg) ^ (lc & 7)) * 8;
  const int sl1 = ((4 + lg) ^ (lc & 7)) * 8;

  f32x4 acc[4][4] = {};

  stA(0, 0); stB(0, 0);
  stA(1, 1); stB(1, 1);

  for (int kt = 0; kt < NT; ++kt) {
    const int bc = kt % 3;
    if (kt + 2 < NT) {
      const int bs = (kt + 2) % 3;
      stA(kt + 2, bs); stB(kt + 2, bs);
      asm volatile("s_waitcnt vmcnt(12)" ::: "memory");
    } else if (kt + 1 < NT) {
      asm volatile("s_waitcnt vmcnt(6)" ::: "memory");
    } else {
      asm volatile("s_waitcnt vmcnt(0)" ::: "memory");
    }
    __builtin_amdgcn_s_barrier();
    asm volatile("" ::: "memory");

    const int ab = bc * 16384 + (wm * 64 + lc) * 64;
    const int bb = 49152 + bc * 8192 + (wn * 64 + lc) * 64;
    bf16x8 afr[4][2], bfr[4][2];
#pragma unroll
    for (int i = 0; i < 4; ++i) {
      afr[i][0] = *(const bf16x8*)&Sm[ab + i * 1024 + sl0];
      afr[i][1] = *(const bf16x8*)&Sm[ab + i * 1024 + sl1];
    }
#pragma unroll
    for (int j = 0; j < 4; ++j) {
      bfr[j][0] = *(const bf16x8*)&Sm[bb + j * 1024 + sl0];
      bfr[j][1] = *(const bf16x8*)&Sm[bb + j * 1024 + sl1];
    }
#pragma unroll
    for (int i = 0; i < 4; ++i)
#pragma unroll
      for (int j = 0; j < 4; ++j) {
        acc[i][j] = __builtin_amdgcn_mfma_f32_16x16x32_bf16(afr[i][0], bfr[j][0], acc[i][j], 0, 0, 0);
        acc[i][j] = __builtin_amdgcn_mfma_f32_16x16x32_bf16(afr[i][1], bfr[j][1], acc[i][j], 0, 0, 0);
      }
    asm volatile("" ::: "memory");
    __builtin_amdgcn_s_barrier();
  }

#pragma unroll
  for (int i = 0; i < 4; ++i) {
    const int row = bm * 256 + wm * 64 + i * 16 + lg * 4;
#pragma unroll
    for (int j = 0; j < 4; ++j) {
      const int col = bn * 128 + wn * 64 + j * 16 + lc;
      const float bv = bias[col];
#pragma unroll
      for (int rg = 0; rg < 4; ++rg) {
        const float v = (acc[i][j][rg] + bv) * scale;
        if (OUT_BF16)
          ((bf16_t*)outp)[(size_t)(row + rg) * E_ + col] = (bf16_t)v;
        else
          ((float*)outp)[(size_t)(row + rg) * E_ + col] = v;
      }
    }
  }
}

// ---------------- uniform causal-256 flash instance (one (scale,instance) per block) --
__global__ __launch_bounds__(512, 4) void attn_inst(
    const bf16_t* __restrict__ Q, const bf16_t* __restrict__ K,
    const bf16_t* __restrict__ V, bf16_t* __restrict__ Ob,
    float* __restrict__ Lse) {
  __shared__ alignas(16) bf16_t Ks[256][72];   // 36864 B
  __shared__ alignas(16) bf16_t Vt[64][264];   // 33792 B
  __shared__ alignas(16) bf16_t Pw[8][16][40]; // 10240 B  (80896 B -> 2 blocks/CU)

  const int bid = blockIdx.x;
  int s, ibase;
  if (bid < 512)      { s = 0; ibase = 0; }
  else if (bid < 768) { s = 1; ibase = 512; }
  else if (bid < 896) { s = 2; ibase = 768; }
  else if (bid < 960) { s = 3; ibase = 896; }
  else                { s = 4; ibase = 960; }
  const int inst = bid - ibase;
  const int h = inst & 15;
  const int nseg_log = 4 - s;
  const int seg = (inst >> 4) & ((1 << nseg_log) - 1);
  const int b = inst >> (4 + nseg_log);
  const int g = h >> (4 - s);      // dilation offset for this head group

  const int t = threadIdx.x;
  const int lane = t & 63;
  const int wv = t >> 6;
  const int lc = lane & 15;
  const int lg = lane >> 4;

  // ---- stage K (row-major, padded) and V (transposed) ----
  {
    const int row = t >> 1, ch = (t & 1) * 32;
    const int tk = ((seg * 256 + row) << s) + g;
    const size_t off = ((size_t)b * T_ + tk) * E_ + h * 64 + ch;
    const bf16_t* Kg = K + off;
    const bf16_t* Vg = V + off;
#pragma unroll
    for (int j = 0; j < 4; ++j)
      *(bf16x8*)&Ks[row][ch + j * 8] = *(const bf16x8*)(Kg + j * 8);
#pragma unroll
    for (int j = 0; j < 4; ++j) {
      bf16x8 va = *(const bf16x8*)(Vg + j * 8);
#pragma unroll
      for (int e = 0; e < 8; ++e) Vt[ch + j * 8 + e][row] = va[e];
    }
  }
  __syncthreads();

  const size_t rowbase = (size_t)(b * H_ + h) * (T_ >> s) + seg * 256;

#pragma unroll
  for (int sel = 0; sel < 2; ++sel) {
    const int tile = sel ? (15 - wv) : wv;   // causal load-balance pairing
    const int q = tile * 16 + lc;            // this lane's query row (swapped layout)

    const int tq = ((seg * 256 + q) << s) + g;
    const bf16_t* Qg = Q + ((size_t)b * T_ + tq) * E_ + h * 64 + lg * 8;
    bf16x8 qfrag0 = *(const bf16x8*)(Qg);
    bf16x8 qfrag1 = *(const bf16x8*)(Qg + 32);

    float m = -INFINITY, Z = 0.0f;
    f32x4 Oa[4] = {};

    const int nkb = tile / 2 + 1;
    const int diag = tile / 2;
    for (int kb = 0; kb < nkb; ++kb) {
      // ---- S^T = K Q^T (32k x 16q): lane holds S[key=kt*16+lg*4+rg][q=lc] ----
      f32x4 sacc[2] = {};
      __builtin_amdgcn_s_setprio(1);
#pragma unroll
      for (int kt = 0; kt < 2; ++kt) {
        bf16x8 kf0 = *(const bf16x8*)&Ks[kb * 32 + kt * 16 + lc][lg * 8];
        bf16x8 kf1 = *(const bf16x8*)&Ks[kb * 32 + kt * 16 + lc][32 + lg * 8];
        sacc[kt] = __builtin_amdgcn_mfma_f32_16x16x32_bf16(kf0, qfrag0, sacc[kt], 0, 0, 0);
        sacc[kt] = __builtin_amdgcn_mfma_f32_16x16x32_bf16(kf1, qfrag1, sacc[kt], 0, 0, 0);
      }
      __builtin_amdgcn_s_setprio(0);
      if (kb == diag) {
#pragma unroll
        for (int kt = 0; kt < 2; ++kt)
#pragma unroll
          for (int rg = 0; rg < 4; ++rg)
            if (kb * 32 + kt * 16 + lg * 4 + rg > q) sacc[kt][rg] = -1e30f;
      }
      // ---- online softmax: one q per lane ----
      float pm = fmaxf(fmaxf(fmaxf(sacc[0][0], sacc[0][1]), fmaxf(sacc[0][2], sacc[0][3])),
                       fmaxf(fmaxf(sacc[1][0], sacc[1][1]), fmaxf(sacc[1][2], sacc[1][3])));
      pm = fmaxf(pm, __shfl_xor(pm, 16));
      pm = fmaxf(pm, __shfl_xor(pm, 32));
      const float nm = fmaxf(m, pm);
      const float crr = __expf(m - nm);
      m = nm;
      float psum = 0.0f;
#pragma unroll
      for (int kt = 0; kt < 2; ++kt)
#pragma unroll
        for (int rg = 0; rg < 4; ++rg) {
          const float p = __expf(sacc[kt][rg] - nm);
          psum += p;
          Pw[wv][lc][kt * 16 + lg * 4 + rg] = (bf16_t)p;
        }
      psum += __shfl_xor(psum, 16);
      psum += __shfl_xor(psum, 32);
      Z = Z * crr + psum;
#pragma unroll
      for (int dt = 0; dt < 4; ++dt)
#pragma unroll
        for (int rg = 0; rg < 4; ++rg) Oa[dt][rg] *= crr;
      // ---- O^T += V^T P^T: A=Vt rows (d), B=P rows (q) ----
      bf16x8 pb = *(const bf16x8*)&Pw[wv][lc][lg * 8];
      __builtin_amdgcn_s_setprio(1);
#pragma unroll
      for (int dt = 0; dt < 4; ++dt) {
        bf16x8 vf = *(const bf16x8*)&Vt[dt * 16 + lc][kb * 32 + lg * 8];
        Oa[dt] = __builtin_amdgcn_mfma_f32_16x16x32_bf16(vf, pb, Oa[dt], 0, 0, 0);
      }
      __builtin_amdgcn_s_setprio(0);
    }

    // ---- epilogue: lane holds O[q=lc][d=dt*16+lg*4+rg] ----
    const float lse = m + __logf(Z);
    const float iZ = 1.0f / Z;
    bf16_t* orow = Ob + OB_OFF[s] + (rowbase + q) * 64 + lg * 4;
#pragma unroll
    for (int dt = 0; dt < 4; ++dt) {
      bf16x4 ov;
      ov[0] = (bf16_t)(Oa[dt][0] * iZ);
      ov[1] = (bf16_t)(Oa[dt][1] * iZ);
      ov[2] = (bf16_t)(Oa[dt][2] * iZ);
      ov[3] = (bf16_t)(Oa[dt][3] * iZ);
      *(bf16x4*)(orow + dt * 16) = ov;
    }
    if (lg == 0) Lse[LSE_OFF[s] + rowbase + q] = lse;
  }
}

// ---------------- merge scales (online LSE) + finalize to bf16 y ----------------
__global__ __launch_bounds__(256) void attn_merge(const bf16_t* __restrict__ Ob,
                                                  const float* __restrict__ Lse,
                                                  bf16_t* __restrict__ Y) {
  const int gtid = blockIdx.x * 256 + threadIdx.x;  // M*E/8 threads
  const int d8 = gtid & 7;
  const int h = (gtid >> 3) & 15;
  const int tt = (gtid >> 7) & (T_ - 1);
  const int b = gtid >> 19;

  float m = -INFINITY, S = 0.0f;
  float acc[8];
#pragma unroll
  for (int j = 0; j < 8; ++j) acc[j] = 0.0f;

#pragma unroll
  for (int s = 0; s < 5; ++s) {
    const int r = 1 << s;
    const int g = h >> (4 - s);
    if ((tt & (r - 1)) != g) continue;   // (t,h) not covered at this scale
    const size_t idx = (size_t)(b * H_ + h) * (T_ >> s) + (tt >> s);
    const float lse = Lse[LSE_OFF[s] + idx];
    const bf16x8 ov = *(const bf16x8*)(Ob + OB_OFF[s] + idx * 64 + d8 * 8);
    const float nM = fmaxf(m, lse);
    const float a = __expf(m - nM);
    const float e = __expf(lse - nM);
#pragma unroll
    for (int j = 0; j < 8; ++j) acc[j] = acc[j] * a + (float)ov[j] * e;
    S = S * a + e;
    m = nM;
  }

  const float invS = 1.0f / S;
  bf16x8 o;
#pragma unroll
  for (int j = 0; j < 8; ++j) o[j] = (bf16_t)(acc[j] * invS);
  *(bf16x8*)(Y + (size_t)gtid * 8) = o;
}

extern "C" void kernel_launch(void* const* d_in, const int* in_sizes, int n_in,
                              void* d_out, int out_size, void* d_ws, size_t ws_size,
                              hipStream_t stream) {
  (void)in_sizes; (void)n_in; (void)out_size; (void)ws_size;
  const float* x  = (const float*)d_in[0];
  const float* wq = (const float*)d_in[1];
  const float* bq = (const float*)d_in[2];
  const float* wk = (const float*)d_in[3];
  const float* bk = (const float*)d_in[4];
  const float* wv = (const float*)d_in[5];
  const float* bv = (const float*)d_in[6];
  const float* wo = (const float*)d_in[7];
  const float* bo = (const float*)d_in[8];

  char* p = (char*)d_ws;
  auto take = [&](size_t bytes) {
    char* q = p;
    p += (bytes + 255) & ~(size_t)255;
    return (void*)q;
  };
  bf16_t* wq_t = (bf16_t*)take((size_t)E_ * E_ * 2);  // wq_t/wk_t/wv_t contiguous
  bf16_t* wk_t = (bf16_t*)take((size_t)E_ * E_ * 2);
  bf16_t* wv_t = (bf16_t*)take((size_t)E_ * E_ * 2);
  bf16_t* wo_t = (bf16_t*)take((size_t)E_ * E_ * 2);
  bf16_t* xb   = (bf16_t*)take((size_t)M_ * E_ * 2);
  bf16_t* qb   = (bf16_t*)take((size_t)M_ * E_ * 2);  // qb/kbuf/vbuf contiguous
  bf16_t* kbuf = (bf16_t*)take((size_t)M_ * E_ * 2);
  bf16_t* vbuf = (bf16_t*)take((size_t)M_ * E_ * 2);
  bf16_t* yb   = (bf16_t*)take((size_t)M_ * E_ * 2);
  bf16_t* Ob   = (bf16_t*)take(OB_TOTAL * 2);
  float*  Lse  = (float*)take(LSE_TOTAL * 4);
  (void)wk_t; (void)wv_t;

  cvt_f32_bf16<<<M_ * E_ / 1024, 256, 0, stream>>>(x, xb);
  cvt_transpose_w<<<dim3(32, 32, 4), 256, 0, stream>>>(wq, wk, wv, wo, wq_t, wk_t, wv_t, wo_t);

  // Fused Q/K/V projection: 256x256 tiles, 8-phase schedule, grid (32, 12).
  gemm8ph<true, true><<<dim3(M_ / 256, 12), 512, 0, stream>>>(
      xb, wq_t, bq, bk, bv, qb);

  // 992 uniform causal-256 flash instances (all scales, one dispatch).
  attn_inst<<<992, 512, 0, stream>>>(qb, kbuf, vbuf, Ob, Lse);

  // Order-free LSE merge + finalize.
  attn_merge<<<M_ * E_ / 8 / 256, 256, 0, stream>>>(Ob, Lse, yb);

  // Output projection: grid (32, 8) = 256 blocks = 1 exact CU-wave.
  gemm_dp<false, false><<<dim3(M_ / 256, 8), 512, 0, stream>>>(
      yb, wo_t, bo, bo, bo, d_out);
}

// Round 10
// 137.990 us; speedup vs baseline: 1.0514x; 1.0514x over previous
//
#include <hip/hip_runtime.h>
#include <hip/hip_bf16.h>

typedef __bf16 bf16_t;
typedef __bf16 bf16x8 __attribute__((ext_vector_type(8)));
typedef __bf16 bf16x4 __attribute__((ext_vector_type(4)));
typedef float f32x4 __attribute__((ext_vector_type(4)));
typedef int vint4 __attribute__((ext_vector_type(4)));

#define AS1 __attribute__((address_space(1)))
#define AS3 __attribute__((address_space(3)))

constexpr int B_ = 2, T_ = 4096, E_ = 1024, H_ = 16;
constexpr int M_ = B_ * T_;   // 8192 token rows

// Compact per-scale partial buffers (elem offsets). Scale s: B*H*(T>>s) rows.
__device__ constexpr size_t OB_OFF[5]  = {0, 8388608, 12582912, 14680064, 15728640};
__device__ constexpr size_t LSE_OFF[5] = {0, 131072, 196608, 229376, 245760};
constexpr size_t OB_TOTAL  = 16252928;  // elems (bf16)
constexpr size_t LSE_TOTAL = 253952;    // elems (f32)

// ---------------- f32 -> bf16 elementwise ----------------
__global__ __launch_bounds__(256) void cvt_f32_bf16(const float* __restrict__ in,
                                                    bf16_t* __restrict__ out) {
  int i = (blockIdx.x * 256 + threadIdx.x) * 4;
  const float4 v = *(const float4*)(in + i);
  bf16x4 o;
  o[0] = (bf16_t)v.x; o[1] = (bf16_t)v.y; o[2] = (bf16_t)v.z; o[3] = (bf16_t)v.w;
  *(bf16x4*)(out + i) = o;
}

// ---------------- weights: f32 [K][N] -> bf16 [N][K] (transposed) ----------------
__global__ __launch_bounds__(256) void cvt_transpose_w(
    const float* __restrict__ w0, const float* __restrict__ w1,
    const float* __restrict__ w2, const float* __restrict__ w3,
    bf16_t* __restrict__ o0, bf16_t* __restrict__ o1,
    bf16_t* __restrict__ o2, bf16_t* __restrict__ o3) {
  __shared__ float tile[32][33];
  const float* src; bf16_t* dst;
  switch (blockIdx.z) {
    case 0: src = w0; dst = o0; break;
    case 1: src = w1; dst = o1; break;
    case 2: src = w2; dst = o2; break;
    default: src = w3; dst = o3; break;
  }
  const int n0 = blockIdx.x * 32, k0 = blockIdx.y * 32;
  const int tx = threadIdx.x & 31, ty = threadIdx.x >> 5;  // 32 x 8
#pragma unroll
  for (int i = 0; i < 32; i += 8)
    tile[ty + i][tx] = src[(size_t)(k0 + ty + i) * E_ + n0 + tx];
  __syncthreads();
#pragma unroll
  for (int i = 0; i < 32; i += 8)
    dst[(size_t)(n0 + ty + i) * E_ + k0 + tx] = (bf16_t)tile[tx][ty + i];
}

// ---------------- 256x128 pipelined GEMM (best-measured: R7, 806 TF) -----------------
// Tile 256x128, BK=64, 512 thr = 8 waves (4M x 2N), wave 64x64, acc[4][4].
// 3-buffer LDS rotation, stage 2 tiles ahead, counted vmcnt(12) (never drain
// mid-loop). Source-side XOR swizzle, LDS linear (conflict-free, R6-verified).
template <bool OUT_BF16, bool QKV>
__global__ __launch_bounds__(512, 1) void gemm_dp(
    const bf16_t* __restrict__ A, const bf16_t* __restrict__ BT,
    const float* __restrict__ bias0, const float* __restrict__ bias1,
    const float* __restrict__ bias2, void* __restrict__ Cout) {
  constexpr int K = E_;
  constexpr int NT = K / 64;           // 16 K-tiles
  __shared__ bf16_t Sm[73728];         // A: 3x16384 | B: 3x8192  (147456 B)

  const int tid = threadIdx.x;
  const int lane = tid & 63;
  const int wid = tid >> 6;
  const int wm = wid >> 1, wn = wid & 1;   // 4M x 2N waves
  const int lc = lane & 15, lg = lane >> 4;
  const int bm = blockIdx.x;
  int bn = blockIdx.y;

  const float* bias = bias0;
  float scale = 1.0f;
  void* outp = Cout;
  const bf16_t* Bt = BT;
  if (QKV) {
    const int which = bn >> 3;
    bn &= 7;
    bias = (which == 0) ? bias0 : (which == 1) ? bias1 : bias2;
    scale = (which == 0) ? 0.125f : 1.0f;
    outp = (void*)((bf16_t*)Cout + (size_t)which * M_ * E_);
    Bt += (size_t)which * E_ * E_;
  }

  const int srow = tid >> 3;                      // 0..63
  const int schunk = (tid & 7) ^ (srow & 7);      // source-side swizzle
  const bf16_t* Ag = A + (size_t)(bm * 256 + srow) * K + schunk * 8;
  const bf16_t* Bg = Bt + (size_t)(bn * 128 + srow) * K + schunk * 8;

  auto stA = [&](int kt, int bu) {
#pragma unroll
    for (int l = 0; l < 4; ++l)
      __builtin_amdgcn_global_load_lds(
          (const AS1 void*)(Ag + (size_t)(l * 64) * K + kt * 64),
          (AS3 void*)(Sm + bu * 16384 + l * 4096 + tid * 8), 16, 0, 0);
  };
  auto stB = [&](int kt, int bu) {
#pragma unroll
    for (int l = 0; l < 2; ++l)
      __builtin_amdgcn_global_load_lds(
          (const AS1 void*)(Bg + (size_t)(l * 64) * K + kt * 64),
          (AS3 void*)(Sm + 49152 + bu * 8192 + l * 4096 + tid * 8), 16, 0, 0);
  };

  const int sl0 = ((lg) ^ (lc & 7)) * 8;
  const int sl1 = ((4 + lg) ^ (lc & 7)) * 8;

  f32x4 acc[4][4] = {};

  stA(0, 0); stB(0, 0);
  stA(1, 1); stB(1, 1);

  for (int kt = 0; kt < NT; ++kt) {
    const int bc = kt % 3;
    if (kt + 2 < NT) {
      const int bs = (kt + 2) % 3;
      stA(kt + 2, bs); stB(kt + 2, bs);
      asm volatile("s_waitcnt vmcnt(12)" ::: "memory");
    } else if (kt + 1 < NT) {
      asm volatile("s_waitcnt vmcnt(6)" ::: "memory");
    } else {
      asm volatile("s_waitcnt vmcnt(0)" ::: "memory");
    }
    __builtin_amdgcn_s_barrier();
    asm volatile("" ::: "memory");

    const int ab = bc * 16384 + (wm * 64 + lc) * 64;
    const int bb = 49152 + bc * 8192 + (wn * 64 + lc) * 64;
    bf16x8 afr[4][2], bfr[4][2];
#pragma unroll
    for (int i = 0; i < 4; ++i) {
      afr[i][0] = *(const bf16x8*)&Sm[ab + i * 1024 + sl0];
      afr[i][1] = *(const bf16x8*)&Sm[ab + i * 1024 + sl1];
    }
#pragma unroll
    for (int j = 0; j < 4; ++j) {
      bfr[j][0] = *(const bf16x8*)&Sm[bb + j * 1024 + sl0];
      bfr[j][1] = *(const bf16x8*)&Sm[bb + j * 1024 + sl1];
    }
#pragma unroll
    for (int i = 0; i < 4; ++i)
#pragma unroll
      for (int j = 0; j < 4; ++j) {
        acc[i][j] = __builtin_amdgcn_mfma_f32_16x16x32_bf16(afr[i][0], bfr[j][0], acc[i][j], 0, 0, 0);
        acc[i][j] = __builtin_amdgcn_mfma_f32_16x16x32_bf16(afr[i][1], bfr[j][1], acc[i][j], 0, 0, 0);
      }
    asm volatile("" ::: "memory");
    __builtin_amdgcn_s_barrier();
  }

#pragma unroll
  for (int i = 0; i < 4; ++i) {
    const int row = bm * 256 + wm * 64 + i * 16 + lg * 4;
#pragma unroll
    for (int j = 0; j < 4; ++j) {
      const int col = bn * 128 + wn * 64 + j * 16 + lc;
      const float bv = bias[col];
#pragma unroll
      for (int rg = 0; rg < 4; ++rg) {
        const float v = (acc[i][j][rg] + bv) * scale;
        if (OUT_BF16)
          ((bf16_t*)outp)[(size_t)(row + rg) * E_ + col] = (bf16_t)v;
        else
          ((float*)outp)[(size_t)(row + rg) * E_ + col] = v;
      }
    }
  }
}

// ---------------- uniform causal-256 flash instance, KB=64 softmax batching ----------
// 992 identical blocks, 8 waves, 2 blocks/CU. Swapped-QK: mfma(K,Q) -> lane holds
// S[key][q=lane&15]. Per 64-key block: 8 S-MFMA -> ONE softmax pass over 16 in-lane
// values (2 shfl max, 2 shfl sum, one crr/Z/O-rescale) -> P packed to bf16x4,
// 4 ds_write_b64 -> PV in two 32-key half-passes through Pw (within-wave ordering).
__global__ __launch_bounds__(512, 4) void attn_inst(
    const bf16_t* __restrict__ Q, const bf16_t* __restrict__ K,
    const bf16_t* __restrict__ V, bf16_t* __restrict__ Ob,
    float* __restrict__ Lse) {
  __shared__ alignas(16) bf16_t Ks[256][72];   // 36864 B
  __shared__ alignas(16) bf16_t Vt[64][264];   // 33792 B
  __shared__ alignas(16) bf16_t Pw[8][16][40]; // 10240 B  (80896 B -> 2 blocks/CU)

  const int bid = blockIdx.x;
  int s, ibase;
  if (bid < 512)      { s = 0; ibase = 0; }
  else if (bid < 768) { s = 1; ibase = 512; }
  else if (bid < 896) { s = 2; ibase = 768; }
  else if (bid < 960) { s = 3; ibase = 896; }
  else                { s = 4; ibase = 960; }
  const int inst = bid - ibase;
  const int h = inst & 15;
  const int nseg_log = 4 - s;
  const int seg = (inst >> 4) & ((1 << nseg_log) - 1);
  const int b = inst >> (4 + nseg_log);
  const int g = h >> (4 - s);      // dilation offset for this head group

  const int t = threadIdx.x;
  const int lane = t & 63;
  const int wv = t >> 6;
  const int lc = lane & 15;
  const int lg = lane >> 4;

  // ---- stage K (row-major, padded) and V (transposed) ----
  {
    const int row = t >> 1, ch = (t & 1) * 32;
    const int tk = ((seg * 256 + row) << s) + g;
    const size_t off = ((size_t)b * T_ + tk) * E_ + h * 64 + ch;
    const bf16_t* Kg = K + off;
    const bf16_t* Vg = V + off;
#pragma unroll
    for (int j = 0; j < 4; ++j)
      *(bf16x8*)&Ks[row][ch + j * 8] = *(const bf16x8*)(Kg + j * 8);
#pragma unroll
    for (int j = 0; j < 4; ++j) {
      bf16x8 va = *(const bf16x8*)(Vg + j * 8);
#pragma unroll
      for (int e = 0; e < 8; ++e) Vt[ch + j * 8 + e][row] = va[e];
    }
  }
  __syncthreads();

  const size_t rowbase = (size_t)(b * H_ + h) * (T_ >> s) + seg * 256;

#pragma unroll
  for (int sel = 0; sel < 2; ++sel) {
    const int tile = sel ? (15 - wv) : wv;   // causal load-balance pairing
    const int q = tile * 16 + lc;            // this lane's query row (swapped layout)

    const int tq = ((seg * 256 + q) << s) + g;
    const bf16_t* Qg = Q + ((size_t)b * T_ + tq) * E_ + h * 64 + lg * 8;
    bf16x8 qfrag0 = *(const bf16x8*)(Qg);
    bf16x8 qfrag1 = *(const bf16x8*)(Qg + 32);

    float m = -INFINITY, Z = 0.0f;
    f32x4 Oa[4] = {};

    const int nkb = tile / 4 + 1;   // 64-key blocks (causal)
    const int diag = tile / 4;
    for (int kb = 0; kb < nkb; ++kb) {
      // ---- S^T = K Q^T (64k x 16q): lane holds S[key=kt*16+lg*4+rg][q=lc] ----
      f32x4 sacc[4] = {};
      __builtin_amdgcn_s_setprio(1);
#pragma unroll
      for (int kt = 0; kt < 4; ++kt) {
        bf16x8 kf0 = *(const bf16x8*)&Ks[kb * 64 + kt * 16 + lc][lg * 8];
        bf16x8 kf1 = *(const bf16x8*)&Ks[kb * 64 + kt * 16 + lc][32 + lg * 8];
        sacc[kt] = __builtin_amdgcn_mfma_f32_16x16x32_bf16(kf0, qfrag0, sacc[kt], 0, 0, 0);
        sacc[kt] = __builtin_amdgcn_mfma_f32_16x16x32_bf16(kf1, qfrag1, sacc[kt], 0, 0, 0);
      }
      __builtin_amdgcn_s_setprio(0);
      if (kb == diag) {
#pragma unroll
        for (int kt = 0; kt < 4; ++kt)
#pragma unroll
          for (int rg = 0; rg < 4; ++rg)
            if (kb * 64 + kt * 16 + lg * 4 + rg > q) sacc[kt][rg] = -1e30f;
      }
      // ---- one softmax pass over 16 in-lane scores ----
      float pm = -1e30f;
#pragma unroll
      for (int kt = 0; kt < 4; ++kt) {
        pm = fmaxf(pm, fmaxf(fmaxf(sacc[kt][0], sacc[kt][1]),
                             fmaxf(sacc[kt][2], sacc[kt][3])));
      }
      pm = fmaxf(pm, __shfl_xor(pm, 16));
      pm = fmaxf(pm, __shfl_xor(pm, 32));
      const float nm = fmaxf(m, pm);
      const float crr = __expf(m - nm);
      m = nm;
      float psum = 0.0f;
      bf16x4 pv[4];
#pragma unroll
      for (int kt = 0; kt < 4; ++kt)
#pragma unroll
        for (int rg = 0; rg < 4; ++rg) {
          const float p = __expf(sacc[kt][rg] - nm);
          psum += p;
          pv[kt][rg] = (bf16_t)p;
        }
      psum += __shfl_xor(psum, 16);
      psum += __shfl_xor(psum, 32);
      Z = Z * crr + psum;
#pragma unroll
      for (int dt = 0; dt < 4; ++dt)
#pragma unroll
        for (int rg = 0; rg < 4; ++rg) Oa[dt][rg] *= crr;
      // ---- PV in two 32-key half-passes through Pw ----
#pragma unroll
      for (int hf = 0; hf < 2; ++hf) {
        *(bf16x4*)&Pw[wv][lc][lg * 4]      = pv[hf * 2 + 0];
        *(bf16x4*)&Pw[wv][lc][16 + lg * 4] = pv[hf * 2 + 1];
        bf16x8 pb = *(const bf16x8*)&Pw[wv][lc][lg * 8];
        __builtin_amdgcn_s_setprio(1);
#pragma unroll
        for (int dt = 0; dt < 4; ++dt) {
          bf16x8 vf = *(const bf16x8*)&Vt[dt * 16 + lc][(kb * 2 + hf) * 32 + lg * 8];
          Oa[dt] = __builtin_amdgcn_mfma_f32_16x16x32_bf16(vf, pb, Oa[dt], 0, 0, 0);
        }
        __builtin_amdgcn_s_setprio(0);
      }
    }

    // ---- epilogue: lane holds O[q=lc][d=dt*16+lg*4+rg] ----
    const float lse = m + __logf(Z);
    const float iZ = 1.0f / Z;
    bf16_t* orow = Ob + OB_OFF[s] + (rowbase + q) * 64 + lg * 4;
#pragma unroll
    for (int dt = 0; dt < 4; ++dt) {
      bf16x4 ov;
      ov[0] = (bf16_t)(Oa[dt][0] * iZ);
      ov[1] = (bf16_t)(Oa[dt][1] * iZ);
      ov[2] = (bf16_t)(Oa[dt][2] * iZ);
      ov[3] = (bf16_t)(Oa[dt][3] * iZ);
      *(bf16x4*)(orow + dt * 16) = ov;
    }
    if (lg == 0) Lse[LSE_OFF[s] + rowbase + q] = lse;
  }
}

// ---------------- merge scales (online LSE) + finalize to bf16 y ----------------
__global__ __launch_bounds__(256) void attn_merge(const bf16_t* __restrict__ Ob,
                                                  const float* __restrict__ Lse,
                                                  bf16_t* __restrict__ Y) {
  const int gtid = blockIdx.x * 256 + threadIdx.x;  // M*E/8 threads
  const int d8 = gtid & 7;
  const int h = (gtid >> 3) & 15;
  const int tt = (gtid >> 7) & (T_ - 1);
  const int b = gtid >> 19;

  float m = -INFINITY, S = 0.0f;
  float acc[8];
#pragma unroll
  for (int j = 0; j < 8; ++j) acc[j] = 0.0f;

#pragma unroll
  for (int s = 0; s < 5; ++s) {
    const int r = 1 << s;
    const int g = h >> (4 - s);
    if ((tt & (r - 1)) != g) continue;   // (t,h) not covered at this scale
    const size_t idx = (size_t)(b * H_ + h) * (T_ >> s) + (tt >> s);
    const float lse = Lse[LSE_OFF[s] + idx];
    const bf16x8 ov = *(const bf16x8*)(Ob + OB_OFF[s] + idx * 64 + d8 * 8);
    const float nM = fmaxf(m, lse);
    const float a = __expf(m - nM);
    const float e = __expf(lse - nM);
#pragma unroll
    for (int j = 0; j < 8; ++j) acc[j] = acc[j] * a + (float)ov[j] * e;
    S = S * a + e;
    m = nM;
  }

  const float invS = 1.0f / S;
  bf16x8 o;
#pragma unroll
  for (int j = 0; j < 8; ++j) o[j] = (bf16_t)(acc[j] * invS);
  *(bf16x8*)(Y + (size_t)gtid * 8) = o;
}

extern "C" void kernel_launch(void* const* d_in, const int* in_sizes, int n_in,
                              void* d_out, int out_size, void* d_ws, size_t ws_size,
                              hipStream_t stream) {
  (void)in_sizes; (void)n_in; (void)out_size; (void)ws_size;
  const float* x  = (const float*)d_in[0];
  const float* wq = (const float*)d_in[1];
  const float* bq = (const float*)d_in[2];
  const float* wk = (const float*)d_in[3];
  const float* bk = (const float*)d_in[4];
  const float* wv = (const float*)d_in[5];
  const float* bv = (const float*)d_in[6];
  const float* wo = (const float*)d_in[7];
  const float* bo = (const float*)d_in[8];

  char* p = (char*)d_ws;
  auto take = [&](size_t bytes) {
    char* q = p;
    p += (bytes + 255) & ~(size_t)255;
    return (void*)q;
  };
  bf16_t* wq_t = (bf16_t*)take((size_t)E_ * E_ * 2);  // wq_t/wk_t/wv_t contiguous
  bf16_t* wk_t = (bf16_t*)take((size_t)E_ * E_ * 2);
  bf16_t* wv_t = (bf16_t*)take((size_t)E_ * E_ * 2);
  bf16_t* wo_t = (bf16_t*)take((size_t)E_ * E_ * 2);
  bf16_t* xb   = (bf16_t*)take((size_t)M_ * E_ * 2);
  bf16_t* qb   = (bf16_t*)take((size_t)M_ * E_ * 2);  // qb/kbuf/vbuf contiguous
  bf16_t* kbuf = (bf16_t*)take((size_t)M_ * E_ * 2);
  bf16_t* vbuf = (bf16_t*)take((size_t)M_ * E_ * 2);
  bf16_t* yb   = (bf16_t*)take((size_t)M_ * E_ * 2);
  bf16_t* Ob   = (bf16_t*)take(OB_TOTAL * 2);
  float*  Lse  = (float*)take(LSE_TOTAL * 4);
  (void)wk_t; (void)wv_t;

  cvt_f32_bf16<<<M_ * E_ / 1024, 256, 0, stream>>>(x, xb);
  cvt_transpose_w<<<dim3(32, 32, 4), 256, 0, stream>>>(wq, wk, wv, wo, wq_t, wk_t, wv_t, wo_t);

  // Fused Q/K/V projection: grid (32, 24) = 768 blocks = 3 exact CU-waves.
  gemm_dp<true, true><<<dim3(M_ / 256, 24), 512, 0, stream>>>(
      xb, wq_t, bq, bk, bv, qb);

  // 992 uniform causal-256 flash instances (all scales, one dispatch).
  attn_inst<<<992, 512, 0, stream>>>(qb, kbuf, vbuf, Ob, Lse);

  // Order-free LSE merge + finalize.
  attn_merge<<<M_ * E_ / 8 / 256, 256, 0, stream>>>(Ob, Lse, yb);

  // Output projection: grid (32, 8) = 256 blocks = 1 exact CU-wave.
  gemm_dp<false, false><<<dim3(M_ / 256, 8), 512, 0, stream>>>(
      yb, wo_t, bo, bo, bo, d_out);
}

// Round 11
// 133.255 us; speedup vs baseline: 1.0888x; 1.0355x over previous
//
#include <hip/hip_runtime.h>
#include <hip/hip_bf16.h>

typedef __bf16 bf16_t;
typedef __bf16 bf16x8 __attribute__((ext_vector_type(8)));
typedef __bf16 bf16x4 __attribute__((ext_vector_type(4)));
typedef float f32x4 __attribute__((ext_vector_type(4)));
typedef int vint4 __attribute__((ext_vector_type(4)));

#define AS1 __attribute__((address_space(1)))
#define AS3 __attribute__((address_space(3)))

constexpr int B_ = 2, T_ = 4096, E_ = 1024, H_ = 16;
constexpr int M_ = B_ * T_;   // 8192 token rows

// Compact per-scale partial buffers (elem offsets). Scale s: B*H*(T>>s) rows.
__device__ constexpr size_t OB_OFF[5]  = {0, 8388608, 12582912, 14680064, 15728640};
__device__ constexpr size_t LSE_OFF[5] = {0, 131072, 196608, 229376, 245760};
constexpr size_t OB_TOTAL  = 16252928;  // elems (bf16)
constexpr size_t LSE_TOTAL = 253952;    // elems (f32)

// ---------------- f32 -> bf16 elementwise ----------------
__global__ __launch_bounds__(256) void cvt_f32_bf16(const float* __restrict__ in,
                                                    bf16_t* __restrict__ out) {
  int i = (blockIdx.x * 256 + threadIdx.x) * 4;
  const float4 v = *(const float4*)(in + i);
  bf16x4 o;
  o[0] = (bf16_t)v.x; o[1] = (bf16_t)v.y; o[2] = (bf16_t)v.z; o[3] = (bf16_t)v.w;
  *(bf16x4*)(out + i) = o;
}

// ---------------- weights: f32 [K][N] -> bf16 [N][K] (transposed) ----------------
__global__ __launch_bounds__(256) void cvt_transpose_w(
    const float* __restrict__ w0, const float* __restrict__ w1,
    const float* __restrict__ w2, const float* __restrict__ w3,
    bf16_t* __restrict__ o0, bf16_t* __restrict__ o1,
    bf16_t* __restrict__ o2, bf16_t* __restrict__ o3) {
  __shared__ float tile[32][33];
  const float* src; bf16_t* dst;
  switch (blockIdx.z) {
    case 0: src = w0; dst = o0; break;
    case 1: src = w1; dst = o1; break;
    case 2: src = w2; dst = o2; break;
    default: src = w3; dst = o3; break;
  }
  const int n0 = blockIdx.x * 32, k0 = blockIdx.y * 32;
  const int tx = threadIdx.x & 31, ty = threadIdx.x >> 5;  // 32 x 8
#pragma unroll
  for (int i = 0; i < 32; i += 8)
    tile[ty + i][tx] = src[(size_t)(k0 + ty + i) * E_ + n0 + tx];
  __syncthreads();
#pragma unroll
  for (int i = 0; i < 32; i += 8)
    dst[(size_t)(n0 + ty + i) * E_ + k0 + tx] = (bf16_t)tile[tx][ty + i];
}

// ---------------- 128x128 single-buffer GEMM (R3 structure) + XOR swizzle ------------
// The one-variable A/B vs R3: identical structure (single 32 KB LDS buffer,
// __syncthreads drain, 256 thr = 4 waves 2x2, wave 64x64, acc[4][4], multi-block/CU)
// but with the R6-verified source-side XOR swizzle -> bank conflicts 1.9e7 -> ~0.
// Multi-block co-residency hides the per-tile drain stalls (m114 mechanism).
template <bool OUT_BF16, bool QKV>
__global__ __launch_bounds__(256, 4) void gemm_bt(
    const bf16_t* __restrict__ A, const bf16_t* __restrict__ BT,
    const float* __restrict__ bias0, const float* __restrict__ bias1,
    const float* __restrict__ bias2, void* __restrict__ Cout, float qscale) {
  constexpr int K = E_;
  __shared__ bf16_t As[128 * 64];
  __shared__ bf16_t Bs[128 * 64];
  const int tid = threadIdx.x;
  const int lane = tid & 63;
  const int wave = tid >> 6;
  const int wm = wave >> 1, wn = wave & 1;
  const int lc = lane & 15, lg = lane >> 4;
  const int bm = blockIdx.x;
  int bn = blockIdx.y;

  const float* bias = bias0;
  float scale = 1.0f;
  void* outp = Cout;
  const bf16_t* Bt = BT;
  if (QKV) {
    const int which = bn >> 3;
    bn &= 7;
    bias = (which == 0) ? bias0 : (which == 1) ? bias1 : bias2;
    scale = (which == 0) ? qscale : 1.0f;
    outp = (void*)((bf16_t*)Cout + (size_t)which * M_ * E_);
    Bt += (size_t)which * E_ * E_;
  }

  f32x4 acc[4][4] = {};

  const int lrow = tid >> 3;                    // 0..31
  const int schunk = (tid & 7) ^ (lrow & 7);    // source-side swizzle
  const bf16_t* Ag = A + (size_t)(bm * 128 + lrow) * K + schunk * 8;
  const bf16_t* Bg = Bt + (size_t)(bn * 128 + lrow) * K + schunk * 8;

  const int sl0 = ((0 * 4 + lg) ^ (lc & 7)) * 8;
  const int sl1 = ((1 * 4 + lg) ^ (lc & 7)) * 8;

  for (int k0 = 0; k0 < K; k0 += 64) {
    __syncthreads();
#pragma unroll
    for (int p = 0; p < 4; ++p) {
      __builtin_amdgcn_global_load_lds(
          (const AS1 void*)(Ag + (size_t)(p * 32) * K + k0),
          (AS3 void*)(As + p * 2048 + tid * 8), 16, 0, 0);
      __builtin_amdgcn_global_load_lds(
          (const AS1 void*)(Bg + (size_t)(p * 32) * K + k0),
          (AS3 void*)(Bs + p * 2048 + tid * 8), 16, 0, 0);
    }
    __syncthreads();
#pragma unroll
    for (int kk = 0; kk < 2; ++kk) {
      const int sl = kk ? sl1 : sl0;
      bf16x8 af[4], bfr[4];
#pragma unroll
      for (int i = 0; i < 4; ++i) {
        af[i]  = *(const bf16x8*)&As[(wm * 64 + i * 16 + lc) * 64 + sl];
        bfr[i] = *(const bf16x8*)&Bs[(wn * 64 + i * 16 + lc) * 64 + sl];
      }
#pragma unroll
      for (int i = 0; i < 4; ++i)
#pragma unroll
        for (int j = 0; j < 4; ++j)
          acc[i][j] = __builtin_amdgcn_mfma_f32_16x16x32_bf16(af[i], bfr[j], acc[i][j], 0, 0, 0);
    }
  }

#pragma unroll
  for (int i = 0; i < 4; ++i) {
    const int row = bm * 128 + wm * 64 + i * 16 + lg * 4;
#pragma unroll
    for (int j = 0; j < 4; ++j) {
      const int col = bn * 128 + wn * 64 + j * 16 + lc;
      const float bv = bias[col];
#pragma unroll
      for (int rg = 0; rg < 4; ++rg) {
        const float v = (acc[i][j][rg] + bv) * scale;
        if (OUT_BF16)
          ((bf16_t*)outp)[(size_t)(row + rg) * E_ + col] = (bf16_t)v;
        else
          ((float*)outp)[(size_t)(row + rg) * E_ + col] = v;
      }
    }
  }
}

// ---------------- uniform causal-256 flash instance, base-2 softmax + defer-max ------
// Q comes pre-scaled by 0.125*log2(e), so P = exp2(S - m) directly (no ln2 mul).
// lse is base-2; merge kernel is base-2 too (softmax weights invariant).
// Defer-max (T13): skip crr/Z/Oa rescale when __all(pm - m <= 11.5) (P <= 2^11.5,
// fine in bf16/f32 accum).
__global__ __launch_bounds__(512, 4) void attn_inst(
    const bf16_t* __restrict__ Q, const bf16_t* __restrict__ K,
    const bf16_t* __restrict__ V, bf16_t* __restrict__ Ob,
    float* __restrict__ Lse) {
  __shared__ alignas(16) bf16_t Ks[256][72];   // 36864 B
  __shared__ alignas(16) bf16_t Vt[64][264];   // 33792 B
  __shared__ alignas(16) bf16_t Pw[8][16][40]; // 10240 B  (80896 B -> 2 blocks/CU)

  const int bid = blockIdx.x;
  int s, ibase;
  if (bid < 512)      { s = 0; ibase = 0; }
  else if (bid < 768) { s = 1; ibase = 512; }
  else if (bid < 896) { s = 2; ibase = 768; }
  else if (bid < 960) { s = 3; ibase = 896; }
  else                { s = 4; ibase = 960; }
  const int inst = bid - ibase;
  const int h = inst & 15;
  const int nseg_log = 4 - s;
  const int seg = (inst >> 4) & ((1 << nseg_log) - 1);
  const int b = inst >> (4 + nseg_log);
  const int g = h >> (4 - s);      // dilation offset for this head group

  const int t = threadIdx.x;
  const int lane = t & 63;
  const int wv = t >> 6;
  const int lc = lane & 15;
  const int lg = lane >> 4;

  // ---- stage K (row-major, padded) and V (transposed) ----
  {
    const int row = t >> 1, ch = (t & 1) * 32;
    const int tk = ((seg * 256 + row) << s) + g;
    const size_t off = ((size_t)b * T_ + tk) * E_ + h * 64 + ch;
    const bf16_t* Kg = K + off;
    const bf16_t* Vg = V + off;
#pragma unroll
    for (int j = 0; j < 4; ++j)
      *(bf16x8*)&Ks[row][ch + j * 8] = *(const bf16x8*)(Kg + j * 8);
#pragma unroll
    for (int j = 0; j < 4; ++j) {
      bf16x8 va = *(const bf16x8*)(Vg + j * 8);
#pragma unroll
      for (int e = 0; e < 8; ++e) Vt[ch + j * 8 + e][row] = va[e];
    }
  }
  __syncthreads();

  const size_t rowbase = (size_t)(b * H_ + h) * (T_ >> s) + seg * 256;

#pragma unroll
  for (int sel = 0; sel < 2; ++sel) {
    const int tile = sel ? (15 - wv) : wv;   // causal load-balance pairing
    const int q = tile * 16 + lc;            // this lane's query row (swapped layout)

    const int tq = ((seg * 256 + q) << s) + g;
    const bf16_t* Qg = Q + ((size_t)b * T_ + tq) * E_ + h * 64 + lg * 8;
    bf16x8 qfrag0 = *(const bf16x8*)(Qg);
    bf16x8 qfrag1 = *(const bf16x8*)(Qg + 32);

    float m = -INFINITY, Z = 0.0f;
    f32x4 Oa[4] = {};

    const int nkb = tile / 4 + 1;   // 64-key blocks (causal)
    const int diag = tile / 4;
    for (int kb = 0; kb < nkb; ++kb) {
      // ---- S^T = K Q^T (64k x 16q): lane holds S[key=kt*16+lg*4+rg][q=lc] ----
      f32x4 sacc[4] = {};
      __builtin_amdgcn_s_setprio(1);
#pragma unroll
      for (int kt = 0; kt < 4; ++kt) {
        bf16x8 kf0 = *(const bf16x8*)&Ks[kb * 64 + kt * 16 + lc][lg * 8];
        bf16x8 kf1 = *(const bf16x8*)&Ks[kb * 64 + kt * 16 + lc][32 + lg * 8];
        sacc[kt] = __builtin_amdgcn_mfma_f32_16x16x32_bf16(kf0, qfrag0, sacc[kt], 0, 0, 0);
        sacc[kt] = __builtin_amdgcn_mfma_f32_16x16x32_bf16(kf1, qfrag1, sacc[kt], 0, 0, 0);
      }
      __builtin_amdgcn_s_setprio(0);
      if (kb == diag) {
#pragma unroll
        for (int kt = 0; kt < 4; ++kt)
#pragma unroll
          for (int rg = 0; rg < 4; ++rg)
            if (kb * 64 + kt * 16 + lg * 4 + rg > q) sacc[kt][rg] = -1e30f;
      }
      // ---- base-2 softmax, one pass over 16 in-lane scores, defer-max ----
      float pm = -1e30f;
#pragma unroll
      for (int kt = 0; kt < 4; ++kt) {
        pm = fmaxf(pm, fmaxf(fmaxf(sacc[kt][0], sacc[kt][1]),
                             fmaxf(sacc[kt][2], sacc[kt][3])));
      }
      pm = fmaxf(pm, __shfl_xor(pm, 16));
      pm = fmaxf(pm, __shfl_xor(pm, 32));
      if (!__all(pm - m <= 11.5f)) {
        const float nm = fmaxf(m, pm);
        const float crr = exp2f(m - nm);
        Z *= crr;
#pragma unroll
        for (int dt = 0; dt < 4; ++dt)
#pragma unroll
          for (int rg = 0; rg < 4; ++rg) Oa[dt][rg] *= crr;
        m = nm;
      }
      float psum = 0.0f;
      bf16x4 pv[4];
#pragma unroll
      for (int kt = 0; kt < 4; ++kt)
#pragma unroll
        for (int rg = 0; rg < 4; ++rg) {
          const float p = exp2f(sacc[kt][rg] - m);
          psum += p;
          pv[kt][rg] = (bf16_t)p;
        }
      psum += __shfl_xor(psum, 16);
      psum += __shfl_xor(psum, 32);
      Z += psum;
      // ---- PV in two 32-key half-passes through Pw ----
#pragma unroll
      for (int hf = 0; hf < 2; ++hf) {
        *(bf16x4*)&Pw[wv][lc][lg * 4]      = pv[hf * 2 + 0];
        *(bf16x4*)&Pw[wv][lc][16 + lg * 4] = pv[hf * 2 + 1];
        bf16x8 pb = *(const bf16x8*)&Pw[wv][lc][lg * 8];
        __builtin_amdgcn_s_setprio(1);
#pragma unroll
        for (int dt = 0; dt < 4; ++dt) {
          bf16x8 vf = *(const bf16x8*)&Vt[dt * 16 + lc][(kb * 2 + hf) * 32 + lg * 8];
          Oa[dt] = __builtin_amdgcn_mfma_f32_16x16x32_bf16(vf, pb, Oa[dt], 0, 0, 0);
        }
        __builtin_amdgcn_s_setprio(0);
      }
    }

    // ---- epilogue: lane holds O[q=lc][d=dt*16+lg*4+rg]; lse is base-2 ----
    const float lse = m + log2f(Z);
    const float iZ = 1.0f / Z;
    bf16_t* orow = Ob + OB_OFF[s] + (rowbase + q) * 64 + lg * 4;
#pragma unroll
    for (int dt = 0; dt < 4; ++dt) {
      bf16x4 ov;
      ov[0] = (bf16_t)(Oa[dt][0] * iZ);
      ov[1] = (bf16_t)(Oa[dt][1] * iZ);
      ov[2] = (bf16_t)(Oa[dt][2] * iZ);
      ov[3] = (bf16_t)(Oa[dt][3] * iZ);
      *(bf16x4*)(orow + dt * 16) = ov;
    }
    if (lg == 0) Lse[LSE_OFF[s] + rowbase + q] = lse;
  }
}

// ---------------- merge scales (base-2 online LSE) + finalize to bf16 y --------------
__global__ __launch_bounds__(256) void attn_merge(const bf16_t* __restrict__ Ob,
                                                  const float* __restrict__ Lse,
                                                  bf16_t* __restrict__ Y) {
  const int gtid = blockIdx.x * 256 + threadIdx.x;  // M*E/8 threads
  const int d8 = gtid & 7;
  const int h = (gtid >> 3) & 15;
  const int tt = (gtid >> 7) & (T_ - 1);
  const int b = gtid >> 19;

  float m = -INFINITY, S = 0.0f;
  float acc[8];
#pragma unroll
  for (int j = 0; j < 8; ++j) acc[j] = 0.0f;

#pragma unroll
  for (int s = 0; s < 5; ++s) {
    const int r = 1 << s;
    const int g = h >> (4 - s);
    if ((tt & (r - 1)) != g) continue;   // (t,h) not covered at this scale
    const size_t idx = (size_t)(b * H_ + h) * (T_ >> s) + (tt >> s);
    const float lse = Lse[LSE_OFF[s] + idx];
    const bf16x8 ov = *(const bf16x8*)(Ob + OB_OFF[s] + idx * 64 + d8 * 8);
    const float nM = fmaxf(m, lse);
    const float a = exp2f(m - nM);
    const float e = exp2f(lse - nM);
#pragma unroll
    for (int j = 0; j < 8; ++j) acc[j] = acc[j] * a + (float)ov[j] * e;
    S = S * a + e;
    m = nM;
  }

  const float invS = 1.0f / S;
  bf16x8 o;
#pragma unroll
  for (int j = 0; j < 8; ++j) o[j] = (bf16_t)(acc[j] * invS);
  *(bf16x8*)(Y + (size_t)gtid * 8) = o;
}

extern "C" void kernel_launch(void* const* d_in, const int* in_sizes, int n_in,
                              void* d_out, int out_size, void* d_ws, size_t ws_size,
                              hipStream_t stream) {
  (void)in_sizes; (void)n_in; (void)out_size; (void)ws_size;
  const float* x  = (const float*)d_in[0];
  const float* wq = (const float*)d_in[1];
  const float* bq = (const float*)d_in[2];
  const float* wk = (const float*)d_in[3];
  const float* bk = (const float*)d_in[4];
  const float* wv = (const float*)d_in[5];
  const float* bv = (const float*)d_in[6];
  const float* wo = (const float*)d_in[7];
  const float* bo = (const float*)d_in[8];

  char* p = (char*)d_ws;
  auto take = [&](size_t bytes) {
    char* q = p;
    p += (bytes + 255) & ~(size_t)255;
    return (void*)q;
  };
  bf16_t* wq_t = (bf16_t*)take((size_t)E_ * E_ * 2);  // wq_t/wk_t/wv_t contiguous
  bf16_t* wk_t = (bf16_t*)take((size_t)E_ * E_ * 2);
  bf16_t* wv_t = (bf16_t*)take((size_t)E_ * E_ * 2);
  bf16_t* wo_t = (bf16_t*)take((size_t)E_ * E_ * 2);
  bf16_t* xb   = (bf16_t*)take((size_t)M_ * E_ * 2);
  bf16_t* qb   = (bf16_t*)take((size_t)M_ * E_ * 2);  // qb/kbuf/vbuf contiguous
  bf16_t* kbuf = (bf16_t*)take((size_t)M_ * E_ * 2);
  bf16_t* vbuf = (bf16_t*)take((size_t)M_ * E_ * 2);
  bf16_t* yb   = (bf16_t*)take((size_t)M_ * E_ * 2);
  bf16_t* Ob   = (bf16_t*)take(OB_TOTAL * 2);
  float*  Lse  = (float*)take(LSE_TOTAL * 4);
  (void)wk_t; (void)wv_t;

  cvt_f32_bf16<<<M_ * E_ / 1024, 256, 0, stream>>>(x, xb);
  cvt_transpose_w<<<dim3(32, 32, 4), 256, 0, stream>>>(wq, wk, wv, wo, wq_t, wk_t, wv_t, wo_t);

  // Fused Q/K/V projection: 128x128 tiles, multi-block/CU, swizzled. Q scale
  // folds log2(e) so attention softmax runs in base 2.
  gemm_bt<true, true><<<dim3(M_ / 128, 24), 256, 0, stream>>>(
      xb, wq_t, bq, bk, bv, qb, 0.125f * 1.44269504f);

  // 992 uniform causal-256 flash instances (all scales, one dispatch).
  attn_inst<<<992, 512, 0, stream>>>(qb, kbuf, vbuf, Ob, Lse);

  // Order-free base-2 LSE merge + finalize.
  attn_merge<<<M_ * E_ / 8 / 256, 256, 0, stream>>>(Ob, Lse, yb);

  // Output projection.
  gemm_bt<false, false><<<dim3(M_ / 128, 8), 256, 0, stream>>>(
      yb, wo_t, bo, bo, bo, d_out, 1.0f);
}

// Round 12
// 130.810 us; speedup vs baseline: 1.1091x; 1.0187x over previous
//
#include <hip/hip_runtime.h>
#include <hip/hip_bf16.h>

typedef __bf16 bf16_t;
typedef __bf16 bf16x8 __attribute__((ext_vector_type(8)));
typedef __bf16 bf16x4 __attribute__((ext_vector_type(4)));
typedef float f32x4 __attribute__((ext_vector_type(4)));
typedef int vint4 __attribute__((ext_vector_type(4)));

#define AS1 __attribute__((address_space(1)))
#define AS3 __attribute__((address_space(3)))

constexpr int B_ = 2, T_ = 4096, E_ = 1024, H_ = 16;
constexpr int M_ = B_ * T_;   // 8192 token rows

// Compact per-scale partial buffers (elem offsets). Scale s: B*H*(T>>s) rows.
__device__ constexpr size_t OB_OFF[5]  = {0, 8388608, 12582912, 14680064, 15728640};
__device__ constexpr size_t LSE_OFF[5] = {0, 131072, 196608, 229376, 245760};
constexpr size_t OB_TOTAL  = 16252928;  // elems (bf16)
constexpr size_t LSE_TOTAL = 253952;    // elems (f32)

// ---------------- f32 -> bf16 elementwise ----------------
__global__ __launch_bounds__(256) void cvt_f32_bf16(const float* __restrict__ in,
                                                    bf16_t* __restrict__ out) {
  int i = (blockIdx.x * 256 + threadIdx.x) * 4;
  const float4 v = *(const float4*)(in + i);
  bf16x4 o;
  o[0] = (bf16_t)v.x; o[1] = (bf16_t)v.y; o[2] = (bf16_t)v.z; o[3] = (bf16_t)v.w;
  *(bf16x4*)(out + i) = o;
}

// ---------------- weights: f32 [K][N] -> bf16 [N][K] (transposed) ----------------
__global__ __launch_bounds__(256) void cvt_transpose_w(
    const float* __restrict__ w0, const float* __restrict__ w1,
    const float* __restrict__ w2, const float* __restrict__ w3,
    bf16_t* __restrict__ o0, bf16_t* __restrict__ o1,
    bf16_t* __restrict__ o2, bf16_t* __restrict__ o3) {
  __shared__ float tile[32][33];
  const float* src; bf16_t* dst;
  switch (blockIdx.z) {
    case 0: src = w0; dst = o0; break;
    case 1: src = w1; dst = o1; break;
    case 2: src = w2; dst = o2; break;
    default: src = w3; dst = o3; break;
  }
  const int n0 = blockIdx.x * 32, k0 = blockIdx.y * 32;
  const int tx = threadIdx.x & 31, ty = threadIdx.x >> 5;  // 32 x 8
#pragma unroll
  for (int i = 0; i < 32; i += 8)
    tile[ty + i][tx] = src[(size_t)(k0 + ty + i) * E_ + n0 + tx];
  __syncthreads();
#pragma unroll
  for (int i = 0; i < 32; i += 8)
    dst[(size_t)(n0 + ty + i) * E_ + k0 + tx] = (bf16_t)tile[tx][ty + i];
}

// ---------------- 128x128 single-buffer GEMM + XOR swizzle (R11-measured: 958 TF) ----
// Single 32 KB-buffer LDS, __syncthreads drain, 256 thr = 4 waves 2x2, wave 64x64,
// acc[4][4], multi-block/CU (the co-residency hides drain stalls — m114 mechanism).
// Source-side XOR swizzle keeps ds_read conflict-free (R11: SQ_LDS_BANK_CONFLICT=0).
template <bool OUT_BF16, bool QKV>
__global__ __launch_bounds__(256, 4) void gemm_bt(
    const bf16_t* __restrict__ A, const bf16_t* __restrict__ BT,
    const float* __restrict__ bias0, const float* __restrict__ bias1,
    const float* __restrict__ bias2, void* __restrict__ Cout, float qscale) {
  constexpr int K = E_;
  __shared__ bf16_t As[128 * 64];
  __shared__ bf16_t Bs[128 * 64];
  const int tid = threadIdx.x;
  const int lane = tid & 63;
  const int wave = tid >> 6;
  const int wm = wave >> 1, wn = wave & 1;
  const int lc = lane & 15, lg = lane >> 4;
  const int bm = blockIdx.x;
  int bn = blockIdx.y;

  const float* bias = bias0;
  float scale = 1.0f;
  void* outp = Cout;
  const bf16_t* Bt = BT;
  if (QKV) {
    const int which = bn >> 3;
    bn &= 7;
    bias = (which == 0) ? bias0 : (which == 1) ? bias1 : bias2;
    scale = (which == 0) ? qscale : 1.0f;
    outp = (void*)((bf16_t*)Cout + (size_t)which * M_ * E_);
    Bt += (size_t)which * E_ * E_;
  }

  f32x4 acc[4][4] = {};

  const int lrow = tid >> 3;                    // 0..31
  const int schunk = (tid & 7) ^ (lrow & 7);    // source-side swizzle
  const bf16_t* Ag = A + (size_t)(bm * 128 + lrow) * K + schunk * 8;
  const bf16_t* Bg = Bt + (size_t)(bn * 128 + lrow) * K + schunk * 8;

  const int sl0 = ((0 * 4 + lg) ^ (lc & 7)) * 8;
  const int sl1 = ((1 * 4 + lg) ^ (lc & 7)) * 8;

  for (int k0 = 0; k0 < K; k0 += 64) {
    __syncthreads();
#pragma unroll
    for (int p = 0; p < 4; ++p) {
      __builtin_amdgcn_global_load_lds(
          (const AS1 void*)(Ag + (size_t)(p * 32) * K + k0),
          (AS3 void*)(As + p * 2048 + tid * 8), 16, 0, 0);
      __builtin_amdgcn_global_load_lds(
          (const AS1 void*)(Bg + (size_t)(p * 32) * K + k0),
          (AS3 void*)(Bs + p * 2048 + tid * 8), 16, 0, 0);
    }
    __syncthreads();
#pragma unroll
    for (int kk = 0; kk < 2; ++kk) {
      const int sl = kk ? sl1 : sl0;
      bf16x8 af[4], bfr[4];
#pragma unroll
      for (int i = 0; i < 4; ++i) {
        af[i]  = *(const bf16x8*)&As[(wm * 64 + i * 16 + lc) * 64 + sl];
        bfr[i] = *(const bf16x8*)&Bs[(wn * 64 + i * 16 + lc) * 64 + sl];
      }
#pragma unroll
      for (int i = 0; i < 4; ++i)
#pragma unroll
        for (int j = 0; j < 4; ++j)
          acc[i][j] = __builtin_amdgcn_mfma_f32_16x16x32_bf16(af[i], bfr[j], acc[i][j], 0, 0, 0);
    }
  }

#pragma unroll
  for (int i = 0; i < 4; ++i) {
    const int row = bm * 128 + wm * 64 + i * 16 + lg * 4;
#pragma unroll
    for (int j = 0; j < 4; ++j) {
      const int col = bn * 128 + wn * 64 + j * 16 + lc;
      const float bv = bias[col];
#pragma unroll
      for (int rg = 0; rg < 4; ++rg) {
        const float v = (acc[i][j][rg] + bv) * scale;
        if (OUT_BF16)
          ((bf16_t*)outp)[(size_t)(row + rg) * E_ + col] = (bf16_t)v;
        else
          ((float*)outp)[(size_t)(row + rg) * E_ + col] = v;
      }
    }
  }
}

// ---------------- uniform causal-256 flash instance, base-2 softmax (HW exp) ---------
// Q comes pre-scaled by 0.125*log2(e). P = v_exp_f32(S - m) directly via
// __builtin_amdgcn_exp2f (the HW op IS base-2 — no ln2 mul, no libcall).
// lse base-2 (__builtin_amdgcn_logf = v_log_f32). Defer-max (T13): skip rescale
// when __all(pm - m <= 11.5) — P <= 2^11.5 is fine in bf16/f32 accum.
__global__ __launch_bounds__(512, 4) void attn_inst(
    const bf16_t* __restrict__ Q, const bf16_t* __restrict__ K,
    const bf16_t* __restrict__ V, bf16_t* __restrict__ Ob,
    float* __restrict__ Lse) {
  __shared__ alignas(16) bf16_t Ks[256][72];   // 36864 B
  __shared__ alignas(16) bf16_t Vt[64][264];   // 33792 B
  __shared__ alignas(16) bf16_t Pw[8][16][40]; // 10240 B  (80896 B -> 2 blocks/CU)

  const int bid = blockIdx.x;
  int s, ibase;
  if (bid < 512)      { s = 0; ibase = 0; }
  else if (bid < 768) { s = 1; ibase = 512; }
  else if (bid < 896) { s = 2; ibase = 768; }
  else if (bid < 960) { s = 3; ibase = 896; }
  else                { s = 4; ibase = 960; }
  const int inst = bid - ibase;
  const int h = inst & 15;
  const int nseg_log = 4 - s;
  const int seg = (inst >> 4) & ((1 << nseg_log) - 1);
  const int b = inst >> (4 + nseg_log);
  const int g = h >> (4 - s);      // dilation offset for this head group

  const int t = threadIdx.x;
  const int lane = t & 63;
  const int wv = t >> 6;
  const int lc = lane & 15;
  const int lg = lane >> 4;

  // ---- stage K (row-major, padded) and V (transposed) ----
  {
    const int row = t >> 1, ch = (t & 1) * 32;
    const int tk = ((seg * 256 + row) << s) + g;
    const size_t off = ((size_t)b * T_ + tk) * E_ + h * 64 + ch;
    const bf16_t* Kg = K + off;
    const bf16_t* Vg = V + off;
#pragma unroll
    for (int j = 0; j < 4; ++j)
      *(bf16x8*)&Ks[row][ch + j * 8] = *(const bf16x8*)(Kg + j * 8);
#pragma unroll
    for (int j = 0; j < 4; ++j) {
      bf16x8 va = *(const bf16x8*)(Vg + j * 8);
#pragma unroll
      for (int e = 0; e < 8; ++e) Vt[ch + j * 8 + e][row] = va[e];
    }
  }
  __syncthreads();

  const size_t rowbase = (size_t)(b * H_ + h) * (T_ >> s) + seg * 256;

#pragma unroll
  for (int sel = 0; sel < 2; ++sel) {
    const int tile = sel ? (15 - wv) : wv;   // causal load-balance pairing
    const int q = tile * 16 + lc;            // this lane's query row (swapped layout)

    const int tq = ((seg * 256 + q) << s) + g;
    const bf16_t* Qg = Q + ((size_t)b * T_ + tq) * E_ + h * 64 + lg * 8;
    bf16x8 qfrag0 = *(const bf16x8*)(Qg);
    bf16x8 qfrag1 = *(const bf16x8*)(Qg + 32);

    float m = -INFINITY, Z = 0.0f;
    f32x4 Oa[4] = {};

    const int nkb = tile / 4 + 1;   // 64-key blocks (causal)
    const int diag = tile / 4;
    for (int kb = 0; kb < nkb; ++kb) {
      // ---- S^T = K Q^T (64k x 16q): lane holds S[key=kt*16+lg*4+rg][q=lc] ----
      f32x4 sacc[4] = {};
      __builtin_amdgcn_s_setprio(1);
#pragma unroll
      for (int kt = 0; kt < 4; ++kt) {
        bf16x8 kf0 = *(const bf16x8*)&Ks[kb * 64 + kt * 16 + lc][lg * 8];
        bf16x8 kf1 = *(const bf16x8*)&Ks[kb * 64 + kt * 16 + lc][32 + lg * 8];
        sacc[kt] = __builtin_amdgcn_mfma_f32_16x16x32_bf16(kf0, qfrag0, sacc[kt], 0, 0, 0);
        sacc[kt] = __builtin_amdgcn_mfma_f32_16x16x32_bf16(kf1, qfrag1, sacc[kt], 0, 0, 0);
      }
      __builtin_amdgcn_s_setprio(0);
      if (kb == diag) {
#pragma unroll
        for (int kt = 0; kt < 4; ++kt)
#pragma unroll
          for (int rg = 0; rg < 4; ++rg)
            if (kb * 64 + kt * 16 + lg * 4 + rg > q) sacc[kt][rg] = -1e30f;
      }
      // ---- base-2 softmax, one pass over 16 in-lane scores, defer-max ----
      float pm = -1e30f;
#pragma unroll
      for (int kt = 0; kt < 4; ++kt) {
        pm = fmaxf(pm, fmaxf(fmaxf(sacc[kt][0], sacc[kt][1]),
                             fmaxf(sacc[kt][2], sacc[kt][3])));
      }
      pm = fmaxf(pm, __shfl_xor(pm, 16));
      pm = fmaxf(pm, __shfl_xor(pm, 32));
      if (!__all(pm - m <= 11.5f)) {
        const float nm = fmaxf(m, pm);
        const float crr = __builtin_amdgcn_exp2f(m - nm);
        Z *= crr;
#pragma unroll
        for (int dt = 0; dt < 4; ++dt)
#pragma unroll
          for (int rg = 0; rg < 4; ++rg) Oa[dt][rg] *= crr;
        m = nm;
      }
      float psum = 0.0f;
      bf16x4 pv[4];
#pragma unroll
      for (int kt = 0; kt < 4; ++kt)
#pragma unroll
        for (int rg = 0; rg < 4; ++rg) {
          const float p = __builtin_amdgcn_exp2f(sacc[kt][rg] - m);
          psum += p;
          pv[kt][rg] = (bf16_t)p;
        }
      psum += __shfl_xor(psum, 16);
      psum += __shfl_xor(psum, 32);
      Z += psum;
      // ---- PV in two 32-key half-passes through Pw ----
#pragma unroll
      for (int hf = 0; hf < 2; ++hf) {
        *(bf16x4*)&Pw[wv][lc][lg * 4]      = pv[hf * 2 + 0];
        *(bf16x4*)&Pw[wv][lc][16 + lg * 4] = pv[hf * 2 + 1];
        bf16x8 pb = *(const bf16x8*)&Pw[wv][lc][lg * 8];
        __builtin_amdgcn_s_setprio(1);
#pragma unroll
        for (int dt = 0; dt < 4; ++dt) {
          bf16x8 vf = *(const bf16x8*)&Vt[dt * 16 + lc][(kb * 2 + hf) * 32 + lg * 8];
          Oa[dt] = __builtin_amdgcn_mfma_f32_16x16x32_bf16(vf, pb, Oa[dt], 0, 0, 0);
        }
        __builtin_amdgcn_s_setprio(0);
      }
    }

    // ---- epilogue: lane holds O[q=lc][d=dt*16+lg*4+rg]; lse is base-2 ----
    const float lse = m + __builtin_amdgcn_logf(Z);
    const float iZ = 1.0f / Z;
    bf16_t* orow = Ob + OB_OFF[s] + (rowbase + q) * 64 + lg * 4;
#pragma unroll
    for (int dt = 0; dt < 4; ++dt) {
      bf16x4 ov;
      ov[0] = (bf16_t)(Oa[dt][0] * iZ);
      ov[1] = (bf16_t)(Oa[dt][1] * iZ);
      ov[2] = (bf16_t)(Oa[dt][2] * iZ);
      ov[3] = (bf16_t)(Oa[dt][3] * iZ);
      *(bf16x4*)(orow + dt * 16) = ov;
    }
    if (lg == 0) Lse[LSE_OFF[s] + rowbase + q] = lse;
  }
}

// ---------------- merge scales (base-2 online LSE, HW exp) + finalize ----------------
__global__ __launch_bounds__(256) void attn_merge(const bf16_t* __restrict__ Ob,
                                                  const float* __restrict__ Lse,
                                                  bf16_t* __restrict__ Y) {
  const int gtid = blockIdx.x * 256 + threadIdx.x;  // M*E/8 threads
  const int d8 = gtid & 7;
  const int h = (gtid >> 3) & 15;
  const int tt = (gtid >> 7) & (T_ - 1);
  const int b = gtid >> 19;

  float m = -INFINITY, S = 0.0f;
  float acc[8];
#pragma unroll
  for (int j = 0; j < 8; ++j) acc[j] = 0.0f;

#pragma unroll
  for (int s = 0; s < 5; ++s) {
    const int r = 1 << s;
    const int g = h >> (4 - s);
    if ((tt & (r - 1)) != g) continue;   // (t,h) not covered at this scale
    const size_t idx = (size_t)(b * H_ + h) * (T_ >> s) + (tt >> s);
    const float lse = Lse[LSE_OFF[s] + idx];
    const bf16x8 ov = *(const bf16x8*)(Ob + OB_OFF[s] + idx * 64 + d8 * 8);
    const float nM = fmaxf(m, lse);
    const float a = __builtin_amdgcn_exp2f(m - nM);
    const float e = __builtin_amdgcn_exp2f(lse - nM);
#pragma unroll
    for (int j = 0; j < 8; ++j) acc[j] = acc[j] * a + (float)ov[j] * e;
    S = S * a + e;
    m = nM;
  }

  const float invS = 1.0f / S;
  bf16x8 o;
#pragma unroll
  for (int j = 0; j < 8; ++j) o[j] = (bf16_t)(acc[j] * invS);
  *(bf16x8*)(Y + (size_t)gtid * 8) = o;
}

extern "C" void kernel_launch(void* const* d_in, const int* in_sizes, int n_in,
                              void* d_out, int out_size, void* d_ws, size_t ws_size,
                              hipStream_t stream) {
  (void)in_sizes; (void)n_in; (void)out_size; (void)ws_size;
  const float* x  = (const float*)d_in[0];
  const float* wq = (const float*)d_in[1];
  const float* bq = (const float*)d_in[2];
  const float* wk = (const float*)d_in[3];
  const float* bk = (const float*)d_in[4];
  const float* wv = (const float*)d_in[5];
  const float* bv = (const float*)d_in[6];
  const float* wo = (const float*)d_in[7];
  const float* bo = (const float*)d_in[8];

  char* p = (char*)d_ws;
  auto take = [&](size_t bytes) {
    char* q = p;
    p += (bytes + 255) & ~(size_t)255;
    return (void*)q;
  };
  bf16_t* wq_t = (bf16_t*)take((size_t)E_ * E_ * 2);  // wq_t/wk_t/wv_t contiguous
  bf16_t* wk_t = (bf16_t*)take((size_t)E_ * E_ * 2);
  bf16_t* wv_t = (bf16_t*)take((size_t)E_ * E_ * 2);
  bf16_t* wo_t = (bf16_t*)take((size_t)E_ * E_ * 2);
  bf16_t* xb   = (bf16_t*)take((size_t)M_ * E_ * 2);
  bf16_t* qb   = (bf16_t*)take((size_t)M_ * E_ * 2);  // qb/kbuf/vbuf contiguous
  bf16_t* kbuf = (bf16_t*)take((size_t)M_ * E_ * 2);
  bf16_t* vbuf = (bf16_t*)take((size_t)M_ * E_ * 2);
  bf16_t* yb   = (bf16_t*)take((size_t)M_ * E_ * 2);
  bf16_t* Ob   = (bf16_t*)take(OB_TOTAL * 2);
  float*  Lse  = (float*)take(LSE_TOTAL * 4);
  (void)wk_t; (void)wv_t;

  cvt_f32_bf16<<<M_ * E_ / 1024, 256, 0, stream>>>(x, xb);
  cvt_transpose_w<<<dim3(32, 32, 4), 256, 0, stream>>>(wq, wk, wv, wo, wq_t, wk_t, wv_t, wo_t);

  // Fused Q/K/V projection: 128x128 tiles, multi-block/CU, swizzled. Q scale
  // folds log2(e) so attention softmax runs in base 2.
  gemm_bt<true, true><<<dim3(M_ / 128, 24), 256, 0, stream>>>(
      xb, wq_t, bq, bk, bv, qb, 0.125f * 1.44269504f);

  // 992 uniform causal-256 flash instances (all scales, one dispatch).
  attn_inst<<<992, 512, 0, stream>>>(qb, kbuf, vbuf, Ob, Lse);

  // Order-free base-2 LSE merge + finalize.
  attn_merge<<<M_ * E_ / 8 / 256, 256, 0, stream>>>(Ob, Lse, yb);

  // Output projection.
  gemm_bt<false, false><<<dim3(M_ / 128, 8), 256, 0, stream>>>(
      yb, wo_t, bo, bo, bo, d_out, 1.0f);
}

// Round 13
// 126.179 us; speedup vs baseline: 1.1498x; 1.0367x over previous
//
#include <hip/hip_runtime.h>
#include <hip/hip_bf16.h>

typedef __bf16 bf16_t;
typedef __bf16 bf16x8 __attribute__((ext_vector_type(8)));
typedef __bf16 bf16x4 __attribute__((ext_vector_type(4)));
typedef float f32x4 __attribute__((ext_vector_type(4)));
typedef int vint4 __attribute__((ext_vector_type(4)));

#define AS1 __attribute__((address_space(1)))
#define AS3 __attribute__((address_space(3)))

constexpr int B_ = 2, T_ = 4096, E_ = 1024, H_ = 16;
constexpr int M_ = B_ * T_;   // 8192 token rows

// Compact per-scale partial buffers (elem offsets); scales 1-4 used (s0 merges inline).
__device__ constexpr size_t OB_OFF[5]  = {0, 8388608, 12582912, 14680064, 15728640};
__device__ constexpr size_t LSE_OFF[5] = {0, 131072, 196608, 229376, 245760};
constexpr size_t OB_TOTAL  = 16252928;  // elems (bf16)
constexpr size_t LSE_TOTAL = 253952;    // elems (f32)

// ---------------- f32 -> bf16 elementwise ----------------
__global__ __launch_bounds__(256) void cvt_f32_bf16(const float* __restrict__ in,
                                                    bf16_t* __restrict__ out) {
  int i = (blockIdx.x * 256 + threadIdx.x) * 4;
  const float4 v = *(const float4*)(in + i);
  bf16x4 o;
  o[0] = (bf16_t)v.x; o[1] = (bf16_t)v.y; o[2] = (bf16_t)v.z; o[3] = (bf16_t)v.w;
  *(bf16x4*)(out + i) = o;
}

// ---------------- weights: f32 [K][N] -> bf16 [N][K] (transposed) ----------------
__global__ __launch_bounds__(256) void cvt_transpose_w(
    const float* __restrict__ w0, const float* __restrict__ w1,
    const float* __restrict__ w2, const float* __restrict__ w3,
    bf16_t* __restrict__ o0, bf16_t* __restrict__ o1,
    bf16_t* __restrict__ o2, bf16_t* __restrict__ o3) {
  __shared__ float tile[32][33];
  const float* src; bf16_t* dst;
  switch (blockIdx.z) {
    case 0: src = w0; dst = o0; break;
    case 1: src = w1; dst = o1; break;
    case 2: src = w2; dst = o2; break;
    default: src = w3; dst = o3; break;
  }
  const int n0 = blockIdx.x * 32, k0 = blockIdx.y * 32;
  const int tx = threadIdx.x & 31, ty = threadIdx.x >> 5;  // 32 x 8
#pragma unroll
  for (int i = 0; i < 32; i += 8)
    tile[ty + i][tx] = src[(size_t)(k0 + ty + i) * E_ + n0 + tx];
  __syncthreads();
#pragma unroll
  for (int i = 0; i < 32; i += 8)
    dst[(size_t)(n0 + ty + i) * E_ + k0 + tx] = (bf16_t)tile[tx][ty + i];
}

// ---------------- 128x128 single-buffer GEMM + XOR swizzle (958 TF measured) ---------
template <bool OUT_BF16, bool QKV>
__global__ __launch_bounds__(256, 4) void gemm_bt(
    const bf16_t* __restrict__ A, const bf16_t* __restrict__ BT,
    const float* __restrict__ bias0, const float* __restrict__ bias1,
    const float* __restrict__ bias2, void* __restrict__ Cout, float qscale) {
  constexpr int K = E_;
  __shared__ bf16_t As[128 * 64];
  __shared__ bf16_t Bs[128 * 64];
  const int tid = threadIdx.x;
  const int lane = tid & 63;
  const int wave = tid >> 6;
  const int wm = wave >> 1, wn = wave & 1;
  const int lc = lane & 15, lg = lane >> 4;
  const int bm = blockIdx.x;
  int bn = blockIdx.y;

  const float* bias = bias0;
  float scale = 1.0f;
  void* outp = Cout;
  const bf16_t* Bt = BT;
  if (QKV) {
    const int which = bn >> 3;
    bn &= 7;
    bias = (which == 0) ? bias0 : (which == 1) ? bias1 : bias2;
    scale = (which == 0) ? qscale : 1.0f;
    outp = (void*)((bf16_t*)Cout + (size_t)which * M_ * E_);
    Bt += (size_t)which * E_ * E_;
  }

  f32x4 acc[4][4] = {};

  const int lrow = tid >> 3;                    // 0..31
  const int schunk = (tid & 7) ^ (lrow & 7);    // source-side swizzle
  const bf16_t* Ag = A + (size_t)(bm * 128 + lrow) * K + schunk * 8;
  const bf16_t* Bg = Bt + (size_t)(bn * 128 + lrow) * K + schunk * 8;

  const int sl0 = ((0 * 4 + lg) ^ (lc & 7)) * 8;
  const int sl1 = ((1 * 4 + lg) ^ (lc & 7)) * 8;

  for (int k0 = 0; k0 < K; k0 += 64) {
    __syncthreads();
#pragma unroll
    for (int p = 0; p < 4; ++p) {
      __builtin_amdgcn_global_load_lds(
          (const AS1 void*)(Ag + (size_t)(p * 32) * K + k0),
          (AS3 void*)(As + p * 2048 + tid * 8), 16, 0, 0);
      __builtin_amdgcn_global_load_lds(
          (const AS1 void*)(Bg + (size_t)(p * 32) * K + k0),
          (AS3 void*)(Bs + p * 2048 + tid * 8), 16, 0, 0);
    }
    __syncthreads();
#pragma unroll
    for (int kk = 0; kk < 2; ++kk) {
      const int sl = kk ? sl1 : sl0;
      bf16x8 af[4], bfr[4];
#pragma unroll
      for (int i = 0; i < 4; ++i) {
        af[i]  = *(const bf16x8*)&As[(wm * 64 + i * 16 + lc) * 64 + sl];
        bfr[i] = *(const bf16x8*)&Bs[(wn * 64 + i * 16 + lc) * 64 + sl];
      }
#pragma unroll
      for (int i = 0; i < 4; ++i)
#pragma unroll
        for (int j = 0; j < 4; ++j)
          acc[i][j] = __builtin_amdgcn_mfma_f32_16x16x32_bf16(af[i], bfr[j], acc[i][j], 0, 0, 0);
    }
  }

#pragma unroll
  for (int i = 0; i < 4; ++i) {
    const int row = bm * 128 + wm * 64 + i * 16 + lg * 4;
#pragma unroll
    for (int j = 0; j < 4; ++j) {
      const int col = bn * 128 + wn * 64 + j * 16 + lc;
      const float bv = bias[col];
#pragma unroll
      for (int rg = 0; rg < 4; ++rg) {
        const float v = (acc[i][j][rg] + bv) * scale;
        if (OUT_BF16)
          ((bf16_t*)outp)[(size_t)(row + rg) * E_ + col] = (bf16_t)v;
        else
          ((float*)outp)[(size_t)(row + rg) * E_ + col] = v;
      }
    }
  }
}

// ---------------- uniform causal-256 flash instance, base-2 softmax (HW exp) ---------
// S0=false (LATE): 480 blocks = scales 1-4 -> write compact Ob/Lse.
// S0=true: 512 blocks = scale 0 (covers every (b,t,h)); epilogue merges the <=4
// covering late-scale (Ob,Lse) entries in-register (online base-2 LSE) and writes
// yb directly -- no scale-0 Ob round-trip, no separate merge dispatch.
template <bool S0>
__global__ __launch_bounds__(512, 4) void attn_inst(
    const bf16_t* __restrict__ Q, const bf16_t* __restrict__ K,
    const bf16_t* __restrict__ V, bf16_t* __restrict__ Ob,
    float* __restrict__ Lse, bf16_t* __restrict__ Y) {
  __shared__ alignas(16) bf16_t Ks[256][72];   // 36864 B
  __shared__ alignas(16) bf16_t Vt[64][264];   // 33792 B
  __shared__ alignas(16) bf16_t Pw[8][16][40]; // 10240 B  (80896 B -> 2 blocks/CU)

  const int bid = blockIdx.x;
  int s, ibase;
  if (S0) { s = 0; ibase = 0; }
  else if (bid < 256) { s = 1; ibase = 0; }
  else if (bid < 384) { s = 2; ibase = 256; }
  else if (bid < 448) { s = 3; ibase = 384; }
  else                { s = 4; ibase = 448; }
  const int inst = bid - ibase;
  const int h = inst & 15;
  const int nseg_log = 4 - s;
  const int seg = (inst >> 4) & ((1 << nseg_log) - 1);
  const int b = inst >> (4 + nseg_log);
  const int g = h >> (4 - s);      // dilation offset for this head group

  const int t = threadIdx.x;
  const int lane = t & 63;
  const int wv = t >> 6;
  const int lc = lane & 15;
  const int lg = lane >> 4;

  // ---- stage K (row-major, padded) and V (transposed) ----
  {
    const int row = t >> 1, ch = (t & 1) * 32;
    const int tk = ((seg * 256 + row) << s) + g;
    const size_t off = ((size_t)b * T_ + tk) * E_ + h * 64 + ch;
    const bf16_t* Kg = K + off;
    const bf16_t* Vg = V + off;
#pragma unroll
    for (int j = 0; j < 4; ++j)
      *(bf16x8*)&Ks[row][ch + j * 8] = *(const bf16x8*)(Kg + j * 8);
#pragma unroll
    for (int j = 0; j < 4; ++j) {
      bf16x8 va = *(const bf16x8*)(Vg + j * 8);
#pragma unroll
      for (int e = 0; e < 8; ++e) Vt[ch + j * 8 + e][row] = va[e];
    }
  }
  __syncthreads();

  const size_t rowbase = (size_t)(b * H_ + h) * (T_ >> s) + seg * 256;

#pragma unroll
  for (int sel = 0; sel < 2; ++sel) {
    const int tile = sel ? (15 - wv) : wv;   // causal load-balance pairing
    const int q = tile * 16 + lc;            // this lane's query row (swapped layout)

    const int tq = ((seg * 256 + q) << s) + g;
    const bf16_t* Qg = Q + ((size_t)b * T_ + tq) * E_ + h * 64 + lg * 8;
    bf16x8 qfrag0 = *(const bf16x8*)(Qg);
    bf16x8 qfrag1 = *(const bf16x8*)(Qg + 32);

    float m = -INFINITY, Z = 0.0f;
    f32x4 Oa[4] = {};

    const int nkb = tile / 4 + 1;   // 64-key blocks (causal)
    const int diag = tile / 4;
    for (int kb = 0; kb < nkb; ++kb) {
      // ---- S^T = K Q^T (64k x 16q): lane holds S[key=kt*16+lg*4+rg][q=lc] ----
      f32x4 sacc[4] = {};
      __builtin_amdgcn_s_setprio(1);
#pragma unroll
      for (int kt = 0; kt < 4; ++kt) {
        bf16x8 kf0 = *(const bf16x8*)&Ks[kb * 64 + kt * 16 + lc][lg * 8];
        bf16x8 kf1 = *(const bf16x8*)&Ks[kb * 64 + kt * 16 + lc][32 + lg * 8];
        sacc[kt] = __builtin_amdgcn_mfma_f32_16x16x32_bf16(kf0, qfrag0, sacc[kt], 0, 0, 0);
        sacc[kt] = __builtin_amdgcn_mfma_f32_16x16x32_bf16(kf1, qfrag1, sacc[kt], 0, 0, 0);
      }
      __builtin_amdgcn_s_setprio(0);
      if (kb == diag) {
#pragma unroll
        for (int kt = 0; kt < 4; ++kt)
#pragma unroll
          for (int rg = 0; rg < 4; ++rg)
            if (kb * 64 + kt * 16 + lg * 4 + rg > q) sacc[kt][rg] = -1e30f;
      }
      // ---- base-2 softmax, one pass over 16 in-lane scores, defer-max ----
      float pm = -1e30f;
#pragma unroll
      for (int kt = 0; kt < 4; ++kt) {
        pm = fmaxf(pm, fmaxf(fmaxf(sacc[kt][0], sacc[kt][1]),
                             fmaxf(sacc[kt][2], sacc[kt][3])));
      }
      pm = fmaxf(pm, __shfl_xor(pm, 16));
      pm = fmaxf(pm, __shfl_xor(pm, 32));
      if (!__all(pm - m <= 11.5f)) {
        const float nm = fmaxf(m, pm);
        const float crr = __builtin_amdgcn_exp2f(m - nm);
        Z *= crr;
#pragma unroll
        for (int dt = 0; dt < 4; ++dt)
#pragma unroll
          for (int rg = 0; rg < 4; ++rg) Oa[dt][rg] *= crr;
        m = nm;
      }
      float psum = 0.0f;
      bf16x4 pv[4];
#pragma unroll
      for (int kt = 0; kt < 4; ++kt)
#pragma unroll
        for (int rg = 0; rg < 4; ++rg) {
          const float p = __builtin_amdgcn_exp2f(sacc[kt][rg] - m);
          psum += p;
          pv[kt][rg] = (bf16_t)p;
        }
      psum += __shfl_xor(psum, 16);
      psum += __shfl_xor(psum, 32);
      Z += psum;
      // ---- PV in two 32-key half-passes through Pw ----
#pragma unroll
      for (int hf = 0; hf < 2; ++hf) {
        *(bf16x4*)&Pw[wv][lc][lg * 4]      = pv[hf * 2 + 0];
        *(bf16x4*)&Pw[wv][lc][16 + lg * 4] = pv[hf * 2 + 1];
        bf16x8 pb = *(const bf16x8*)&Pw[wv][lc][lg * 8];
        __builtin_amdgcn_s_setprio(1);
#pragma unroll
        for (int dt = 0; dt < 4; ++dt) {
          bf16x8 vf = *(const bf16x8*)&Vt[dt * 16 + lc][(kb * 2 + hf) * 32 + lg * 8];
          Oa[dt] = __builtin_amdgcn_mfma_f32_16x16x32_bf16(vf, pb, Oa[dt], 0, 0, 0);
        }
        __builtin_amdgcn_s_setprio(0);
      }
    }

    // ---- epilogue: lane holds O[q=lc][d=dt*16+lg*4+rg]; lse is base-2 ----
    const float lse = m + __builtin_amdgcn_logf(Z);
    const float iZ = 1.0f / Z;
    if (!S0) {
      bf16_t* orow = Ob + OB_OFF[s] + (rowbase + q) * 64 + lg * 4;
#pragma unroll
      for (int dt = 0; dt < 4; ++dt) {
        bf16x4 ov;
        ov[0] = (bf16_t)(Oa[dt][0] * iZ);
        ov[1] = (bf16_t)(Oa[dt][1] * iZ);
        ov[2] = (bf16_t)(Oa[dt][2] * iZ);
        ov[3] = (bf16_t)(Oa[dt][3] * iZ);
        *(bf16x4*)(orow + dt * 16) = ov;
      }
      if (lg == 0) Lse[LSE_OFF[s] + rowbase + q] = lse;
    } else {
      // in-register merge of late scales (stream-ordered: their dispatch is done)
      const int t_glob = seg * 256 + q;          // s=0 -> global position
      float o16[4][4];
#pragma unroll
      for (int dt = 0; dt < 4; ++dt)
#pragma unroll
        for (int rg = 0; rg < 4; ++rg) o16[dt][rg] = Oa[dt][rg] * iZ;
      float M = lse, S = 1.0f;
#pragma unroll
      for (int s2 = 1; s2 <= 4; ++s2) {
        const int r = 1 << s2;
        const int gg = h >> (4 - s2);
        if ((t_glob & (r - 1)) != gg) continue;
        const size_t idx = (size_t)(b * H_ + h) * (T_ >> s2) + (t_glob >> s2);
        const float l2 = Lse[LSE_OFF[s2] + idx];
        const bf16_t* orow = Ob + OB_OFF[s2] + idx * 64 + lg * 4;
        const float nM = fmaxf(M, l2);
        const float a = __builtin_amdgcn_exp2f(M - nM);
        const float e = __builtin_amdgcn_exp2f(l2 - nM);
#pragma unroll
        for (int dt = 0; dt < 4; ++dt) {
          const bf16x4 ov = *(const bf16x4*)(orow + dt * 16);
#pragma unroll
          for (int rg = 0; rg < 4; ++rg)
            o16[dt][rg] = o16[dt][rg] * a + (float)ov[rg] * e;
        }
        S = S * a + e;
        M = nM;
      }
      const float invS = 1.0f / S;
      bf16_t* yrow = Y + ((size_t)b * T_ + t_glob) * E_ + h * 64 + lg * 4;
#pragma unroll
      for (int dt = 0; dt < 4; ++dt) {
        bf16x4 ov;
        ov[0] = (bf16_t)(o16[dt][0] * invS);
        ov[1] = (bf16_t)(o16[dt][1] * invS);
        ov[2] = (bf16_t)(o16[dt][2] * invS);
        ov[3] = (bf16_t)(o16[dt][3] * invS);
        *(bf16x4*)(yrow + dt * 16) = ov;
      }
    }
  }
}

extern "C" void kernel_launch(void* const* d_in, const int* in_sizes, int n_in,
                              void* d_out, int out_size, void* d_ws, size_t ws_size,
                              hipStream_t stream) {
  (void)in_sizes; (void)n_in; (void)out_size; (void)ws_size;
  const float* x  = (const float*)d_in[0];
  const float* wq = (const float*)d_in[1];
  const float* bq = (const float*)d_in[2];
  const float* wk = (const float*)d_in[3];
  const float* bk = (const float*)d_in[4];
  const float* wv = (const float*)d_in[5];
  const float* bv = (const float*)d_in[6];
  const float* wo = (const float*)d_in[7];
  const float* bo = (const float*)d_in[8];

  char* p = (char*)d_ws;
  auto take = [&](size_t bytes) {
    char* q = p;
    p += (bytes + 255) & ~(size_t)255;
    return (void*)q;
  };
  bf16_t* wq_t = (bf16_t*)take((size_t)E_ * E_ * 2);  // wq_t/wk_t/wv_t contiguous
  bf16_t* wk_t = (bf16_t*)take((size_t)E_ * E_ * 2);
  bf16_t* wv_t = (bf16_t*)take((size_t)E_ * E_ * 2);
  bf16_t* wo_t = (bf16_t*)take((size_t)E_ * E_ * 2);
  bf16_t* xb   = (bf16_t*)take((size_t)M_ * E_ * 2);
  bf16_t* qb   = (bf16_t*)take((size_t)M_ * E_ * 2);  // qb/kbuf/vbuf contiguous
  bf16_t* kbuf = (bf16_t*)take((size_t)M_ * E_ * 2);
  bf16_t* vbuf = (bf16_t*)take((size_t)M_ * E_ * 2);
  bf16_t* yb   = (bf16_t*)take((size_t)M_ * E_ * 2);
  bf16_t* Ob   = (bf16_t*)take(OB_TOTAL * 2);
  float*  Lse  = (float*)take(LSE_TOTAL * 4);
  (void)wk_t; (void)wv_t;

  cvt_f32_bf16<<<M_ * E_ / 1024, 256, 0, stream>>>(x, xb);
  cvt_transpose_w<<<dim3(32, 32, 4), 256, 0, stream>>>(wq, wk, wv, wo, wq_t, wk_t, wv_t, wo_t);

  // Fused Q/K/V projection: 128x128 tiles, multi-block/CU, swizzled. Q scale
  // folds log2(e) so attention softmax runs in base 2.
  gemm_bt<true, true><<<dim3(M_ / 128, 24), 256, 0, stream>>>(
      xb, wq_t, bq, bk, bv, qb, 0.125f * 1.44269504f);

  // Scales 1-4 (480 blocks) -> compact Ob/Lse.
  attn_inst<false><<<480, 512, 0, stream>>>(qb, kbuf, vbuf, Ob, Lse, yb);
  // Scale 0 (512 blocks) + in-register merge + y write. No merge dispatch.
  attn_inst<true><<<512, 512, 0, stream>>>(qb, kbuf, vbuf, Ob, Lse, yb);

  // Output projection.
  gemm_bt<false, false><<<dim3(M_ / 128, 8), 256, 0, stream>>>(
      yb, wo_t, bo, bo, bo, d_out, 1.0f);
}